// Round 2
// baseline (897.636 us; speedup 1.0000x reference)
//
#include <hip/hip_runtime.h>

#define N_NODES 10000
#define EDGES   160000
#define BATCH   8
#define TT      12
#define HID     64
#define CAP     64       // fixed edge-slot capacity per node (avg deg 16, P(deg>64) ~ 0)

// ---------------- CSR build (fixed-capacity, no scan) ----------------

// fill fixed-cap lists with raw weights; cursor counts per node
__global__ __launch_bounds__(256) void k_fillfix(const int* __restrict__ ei,
                                                 const float* __restrict__ ew,
                                                 int* __restrict__ cur,
                                                 int* __restrict__ csrc,
                                                 float* __restrict__ cnorm) {
  int g = blockIdx.x * 256 + threadIdx.x;
  if (g < EDGES) {
    int s = ei[g], d = ei[EDGES + g];
    int slot = atomicAdd(&cur[d], 1);
    csrc[d * CAP + slot]  = s;
    cnorm[d * CAP + slot] = ew[g];
  }
}

// wave per node: zero pad slots cnt..m (m = pad8(cnt)), deg = 1 + sum(real w), dinv, mcnt
__global__ __launch_bounds__(256) void k_degpad(const int* __restrict__ cur,
                                                int* __restrict__ csrc,
                                                float* __restrict__ cnorm,
                                                float* __restrict__ dinv,
                                                int* __restrict__ mcnt) {
  int n = blockIdx.x * 4 + (threadIdx.x >> 6);
  int lane = threadIdx.x & 63;
  int cnt = cur[n];
  int m = (cnt + 7) & ~7;
  int base = n * CAP;
  if (lane >= cnt && lane < m) { csrc[base + lane] = 0; cnorm[base + lane] = 0.0f; }
  float s = (lane < cnt) ? cnorm[base + lane] : 0.0f;
  #pragma unroll
  for (int off = 32; off > 0; off >>= 1) s += __shfl_xor(s, off, 64);
  if (lane == 0) {
    dinv[n] = 1.0f / sqrtf(s + 1.0f);
    mcnt[n] = m;
  }
}

// merged: blocks 0..2499 = wnorm (cnorm[e] *= dinv[src]*dinv[n]); blocks 2500.. = weight pack
//  p1c [192][128]: row kk: t3=kk>>6, i=kk&63; col: half=col>>6 (t'=10+half), o=col&63
//  p2c [128][64]:  row kk: g=kk>>6 (t1 half), i=kk&63
//  pb1 [128] = tc1_b duplicated
__global__ __launch_bounds__(256) void k_wnormpack(const int* __restrict__ cur,
                                                   const int* __restrict__ csrc,
                                                   const float* __restrict__ dinv,
                                                   float* __restrict__ cnorm,
                                                   const float* __restrict__ tc1w,
                                                   const float* __restrict__ tc2w,
                                                   const float* __restrict__ tc1b,
                                                   float* __restrict__ p1c,
                                                   float* __restrict__ p2c,
                                                   float* __restrict__ pb1) {
  if (blockIdx.x < 2500) {
    int n = blockIdx.x * 4 + (threadIdx.x >> 6);
    int lane = threadIdx.x & 63;
    int cnt = cur[n];
    int m = (cnt + 7) & ~7;
    if (lane < m) {
      int idx = n * CAP + lane;
      cnorm[idx] = cnorm[idx] * dinv[csrc[idx]] * dinv[n];
    }
  } else {
    int g = (blockIdx.x - 2500) * 256 + threadIdx.x;
    if (g < 24576) {
      int kk = g >> 7, col = g & 127;
      int t3 = kk >> 6, i = kk & 63;
      int half = col >> 6, o = col & 63;
      float v;
      if (half == 0) v = tc1w[o * 192 + i * 3 + t3];
      else           v = (t3 == 0) ? 0.0f : tc1w[o * 192 + i * 3 + (t3 - 1)];
      p1c[g] = v;
    } else if (g < 24576 + 8192) {
      int r = g - 24576;
      int kk = r >> 6, o = r & 63;
      int gk = kk >> 6, i = kk & 63;
      p2c[r] = tc2w[o * 192 + i * 3 + gk];
    } else if (g < 24576 + 8192 + 128) {
      int r = g - 24576 - 8192;
      pb1[r] = tc1b[r & 63];
    }
  }
}

// ---------------- GCN layer 1: fused agg(X) @ W1 + b1, relu -> h1[b][n][t3*64+c] ----------------

__global__ __launch_bounds__(256) void k_aggg1(const float* __restrict__ X,
                                               const float* __restrict__ dinv,
                                               const int* __restrict__ mcnt,
                                               const int* __restrict__ csrc,
                                               const float* __restrict__ cnorm,
                                               const float* __restrict__ W1,
                                               const float* __restrict__ b1,
                                               float* __restrict__ h1) {
  int b = blockIdx.x & 7;                    // batch -> XCD affinity
  int grp = blockIdx.x >> 3;                 // 0..2499
  int n = grp * 4 + (threadIdx.x >> 6);
  int lane = threadIdx.x & 63;
  const float2* x0 = (const float2*)(X + (size_t)(b * TT + 9)  * N_NODES * 2);
  const float2* x1 = (const float2*)(X + (size_t)(b * TT + 10) * N_NODES * 2);
  const float2* x2 = (const float2*)(X + (size_t)(b * TT + 11) * N_NODES * 2);
  float a0x = 0.f, a0y = 0.f, a1x = 0.f, a1y = 0.f, a2x = 0.f, a2y = 0.f;
  int m = mcnt[n];
  if (lane < m) {                            // pads have w=0 so they contribute 0 anyway
    int idx = n * CAP + lane;
    float w = cnorm[idx];
    int s = csrc[idx];
    float2 s0 = x0[s], s1 = x1[s], s2v = x2[s];
    a0x = w * s0.x;  a0y = w * s0.y;
    a1x = w * s1.x;  a1y = w * s1.y;
    a2x = w * s2v.x; a2y = w * s2v.y;
  }
  if (lane == 0) {  // self-loop term
    float di = dinv[n];
    float sd = di * di;
    float2 v0 = x0[n], v1 = x1[n], v2 = x2[n];
    a0x += sd * v0.x; a0y += sd * v0.y;
    a1x += sd * v1.x; a1y += sd * v1.y;
    a2x += sd * v2.x; a2y += sd * v2.y;
  }
  #pragma unroll
  for (int off = 32; off > 0; off >>= 1) {
    a0x += __shfl_xor(a0x, off, 64);
    a0y += __shfl_xor(a0y, off, 64);
    a1x += __shfl_xor(a1x, off, 64);
    a1y += __shfl_xor(a1y, off, 64);
    a2x += __shfl_xor(a2x, off, 64);
    a2y += __shfl_xor(a2y, off, 64);
  }
  int c = lane;
  float w0 = W1[c], w1 = W1[64 + c], bc = b1[c];
  size_t ob = ((size_t)(b * N_NODES + n)) * 192 + c;
  h1[ob]       = fmaxf(a0x * w0 + a0y * w1 + bc, 0.0f);
  h1[ob + 64]  = fmaxf(a1x * w0 + a1y * w1 + bc, 0.0f);
  h1[ob + 128] = fmaxf(a2x * w0 + a2y * w1 + bc, 0.0f);
}

// ---------------- GCN layer 2 aggregation: merged 3-t3 single pass, readlane broadcast ----
// Wave per (b,n), lane = channel. Edge (src,w) staged once (single <=64 chunk) in lane
// regs, broadcast per edge via v_readlane; 3 independent gathers per edge (t3 planes).
__global__ __launch_bounds__(256) void k_agg3m(const float* __restrict__ h1,
                                               const float* __restrict__ dinv,
                                               const int* __restrict__ mcnt,
                                               const int* __restrict__ csrc,
                                               const float* __restrict__ cnorm,
                                               float* __restrict__ ah) {
  int b = blockIdx.x & 7;                    // batch -> XCD affinity
  int grp = blockIdx.x >> 3;                 // 0..2499
  int n = grp * 4 + (threadIdx.x >> 6);
  int c = threadIdx.x & 63;
  const float* hb = h1 + (size_t)b * N_NODES * 192;
  float acc0 = 0.f, acc1 = 0.f, acc2 = 0.f;
  int m = mcnt[n];                           // <= 64, multiple of 8
  int idx = n * CAP + c;
  int ic = (c < m) ? idx : n * CAP;
  int sv = csrc[ic] * 192;                   // float offset of source row
  float wf = (c < m) ? cnorm[idx] : 0.0f;
  int wb = __float_as_int(wf);
  for (int e = 0; e < m; e += 8) {
    #pragma unroll
    for (int u = 0; u < 8; u++) {
      int   off = __builtin_amdgcn_readlane(sv, e + u);
      float w   = __int_as_float(__builtin_amdgcn_readlane(wb, e + u));
      const float* p = hb + off;
      acc0 += w * p[c];
      acc1 += w * p[64 + c];
      acc2 += w * p[128 + c];
    }
  }
  float di = dinv[n];
  float s2 = di * di;
  const float* sr = hb + (size_t)n * 192;
  size_t ob = ((size_t)(b * N_NODES + n)) * 192 + c;
  ah[ob]       = acc0 + s2 * sr[c];
  ah[ob + 64]  = acc1 + s2 * sr[64 + c];
  ah[ob + 128] = acc2 + s2 * sr[128 + c];
}

// ---------------- fused epilogue v3: weights from GLOBAL (L1/L2), A-only LDS ----------------
// Theory: v2 was DS-pipe-bound (~780 ds_read_b128/wave x 12cy x 39 waves/CU ~ 150us ~ measured
// 137us). Weights are shared by all 2500 blocks -> read w-fragments straight from global
// (VMEM pipe, L1/L2-resident), delete the Ws LDS buffer + its ~46 staging barriers.
// DS ops/wave: 780 -> ~368; barriers -> 3. LDS = 51,200B -> still 3 blocks/CU.
__global__ __launch_bounds__(256, 3) void k_fused(const float* __restrict__ ah,
                                                  const float* __restrict__ W2,
                                                  const float* __restrict__ b2,
                                                  const float* __restrict__ p1c,
                                                  const float* __restrict__ pb1,
                                                  const float* __restrict__ p2c,
                                                  const float* __restrict__ tc2b,
                                                  const float* __restrict__ ow,
                                                  const float* __restrict__ obp,
                                                  float* __restrict__ out) {
  __shared__ __align__(16) float smem[12800];    // 51,200 B
  float* spL = smem;                             // [32][196] = 6272
  float* ovl = smem + 6272;                      // As [96][68]=6528  |  t1L [32][132]=4224
  float* As  = ovl;
  float* t1L = ovl;
  int tid = threadIdx.x;
  size_t nodeBase = (size_t)blockIdx.x * 32;     // in (b*N+n) units
  const float* A = ah + nodeBase * 192;          // 96 rows (n,t3) x 64, row-major

  // ---- stage A once: 96x64 -> As[96][68] (full k-width, single barrier)
  #pragma unroll
  for (int rep = 0; rep < 6; rep++) {            // 1536 float4
    int idx = rep * 256 + tid;
    int m = idx >> 4, q4 = (idx & 15) * 4;
    *(float4*)&As[m * 68 + q4] = *(const float4*)(A + m * 64 + q4);
  }
  __syncthreads();

  // ---- phase 1: sp = relu(A[96x64] @ W2[64x64] + b2) -> spL[n][t3*64+c]; W2 from global
  {
    int ty = tid >> 4, tx = tid & 15;            // rows 6ty+i, cols 4tx+j
    float acc[6][4] = {{0.f}};
    for (int k0 = 0; k0 < 64; k0 += 16) {
      #pragma unroll
      for (int kq = 0; kq < 4; kq++) {
        int k = k0 + kq * 4;
        float4 a[6], w[4];
        #pragma unroll
        for (int i = 0; i < 6; i++) a[i] = *(const float4*)&As[(6 * ty + i) * 68 + k];
        #pragma unroll
        for (int kk = 0; kk < 4; kk++) w[kk] = *(const float4*)(W2 + (size_t)(k + kk) * 64 + 4 * tx);
        #pragma unroll
        for (int i = 0; i < 6; i++) {
          float av[4] = {a[i].x, a[i].y, a[i].z, a[i].w};
          #pragma unroll
          for (int kk = 0; kk < 4; kk++) {
            acc[i][0] += av[kk] * w[kk].x;
            acc[i][1] += av[kk] * w[kk].y;
            acc[i][2] += av[kk] * w[kk].z;
            acc[i][3] += av[kk] * w[kk].w;
          }
        }
      }
    }
    float4 bv = *(const float4*)(b2 + 4 * tx);
    #pragma unroll
    for (int i = 0; i < 6; i++) {
      int m = 6 * ty + i;
      int n = m / 3, t3 = m % 3;
      float4 o;
      o.x = fmaxf(acc[i][0] + bv.x, 0.0f);
      o.y = fmaxf(acc[i][1] + bv.y, 0.0f);
      o.z = fmaxf(acc[i][2] + bv.z, 0.0f);
      o.w = fmaxf(acc[i][3] + bv.w, 0.0f);
      *(float4*)&spL[n * 196 + t3 * 64 + 4 * tx] = o;
    }
  }
  __syncthreads();                               // spL visible; As reads all done

  // ---- phase 2: t1 = relu(spL[32x192] @ p1c[192x128] + pb1) -> t1L[32][132]; p1c from global
  {
    int ty = tid >> 5, tx = tid & 31;            // rows 4ty+i, cols 4tx+j
    float acc[4][4] = {{0.f}};
    for (int k0 = 0; k0 < 192; k0 += 16) {
      #pragma unroll
      for (int kq = 0; kq < 4; kq++) {
        int k = k0 + kq * 4;
        float4 a[4], w[4];
        #pragma unroll
        for (int i = 0; i < 4; i++) a[i] = *(const float4*)&spL[(4 * ty + i) * 196 + k];
        #pragma unroll
        for (int kk = 0; kk < 4; kk++) w[kk] = *(const float4*)(p1c + (size_t)(k + kk) * 128 + 4 * tx);
        #pragma unroll
        for (int i = 0; i < 4; i++) {
          float av[4] = {a[i].x, a[i].y, a[i].z, a[i].w};
          #pragma unroll
          for (int kk = 0; kk < 4; kk++) {
            acc[i][0] += av[kk] * w[kk].x;
            acc[i][1] += av[kk] * w[kk].y;
            acc[i][2] += av[kk] * w[kk].z;
            acc[i][3] += av[kk] * w[kk].w;
          }
        }
      }
    }
    float4 bv = *(const float4*)(pb1 + 4 * tx);
    #pragma unroll
    for (int i = 0; i < 4; i++) {
      float4 o;
      o.x = fmaxf(acc[i][0] + bv.x, 0.0f);
      o.y = fmaxf(acc[i][1] + bv.y, 0.0f);
      o.z = fmaxf(acc[i][2] + bv.z, 0.0f);
      o.w = fmaxf(acc[i][3] + bv.w, 0.0f);
      *(float4*)&t1L[(4 * ty + i) * 132 + 4 * tx] = o;
    }
  }
  __syncthreads();                               // t1L visible

  // ---- phase 3: last = relu(t1L[32x128] @ p2c[128x64] + tc2b); out = last . ow + ob
  {
    int ty = tid >> 4, tx = tid & 15;            // rows 2ty+i, cols 4tx+j
    float acc[2][4] = {{0.f}};
    for (int k0 = 0; k0 < 128; k0 += 16) {
      #pragma unroll
      for (int kq = 0; kq < 4; kq++) {
        int k = k0 + kq * 4;
        float4 a[2], w[4];
        #pragma unroll
        for (int i = 0; i < 2; i++) a[i] = *(const float4*)&t1L[(2 * ty + i) * 132 + k];
        #pragma unroll
        for (int kk = 0; kk < 4; kk++) w[kk] = *(const float4*)(p2c + (size_t)(k + kk) * 64 + 4 * tx);
        #pragma unroll
        for (int i = 0; i < 2; i++) {
          float av[4] = {a[i].x, a[i].y, a[i].z, a[i].w};
          #pragma unroll
          for (int kk = 0; kk < 4; kk++) {
            acc[i][0] += av[kk] * w[kk].x;
            acc[i][1] += av[kk] * w[kk].y;
            acc[i][2] += av[kk] * w[kk].z;
            acc[i][3] += av[kk] * w[kk].w;
          }
        }
      }
    }
    float4 bv = *(const float4*)(tc2b + 4 * tx);
    float4 o4 = *(const float4*)(ow + 4 * tx);
    float obv = obp[0];
    #pragma unroll
    for (int i = 0; i < 2; i++) {
      float v = fmaxf(acc[i][0] + bv.x, 0.0f) * o4.x
              + fmaxf(acc[i][1] + bv.y, 0.0f) * o4.y
              + fmaxf(acc[i][2] + bv.z, 0.0f) * o4.z
              + fmaxf(acc[i][3] + bv.w, 0.0f) * o4.w;
      v += __shfl_xor(v, 1, 64);
      v += __shfl_xor(v, 2, 64);
      v += __shfl_xor(v, 4, 64);
      v += __shfl_xor(v, 8, 64);
      if (tx == 0) out[nodeBase + 2 * ty + i] = v + obv;
    }
  }
}

// ---------------- launch ----------------

extern "C" void kernel_launch(void* const* d_in, const int* in_sizes, int n_in,
                              void* d_out, int out_size, void* d_ws, size_t ws_size,
                              hipStream_t stream) {
  const float* X    = (const float*)d_in[0];
  const int*   EI   = (const int*)  d_in[1];
  const float* EW   = (const float*)d_in[2];
  const float* W1   = (const float*)d_in[3];
  const float* B1   = (const float*)d_in[4];
  const float* W2   = (const float*)d_in[5];
  const float* B2   = (const float*)d_in[6];
  const float* TC1W = (const float*)d_in[7];
  const float* TC1B = (const float*)d_in[8];
  const float* TC2W = (const float*)d_in[9];
  const float* TC2B = (const float*)d_in[10];
  const float* OW   = (const float*)d_in[11];
  const float* OB   = (const float*)d_in[12];
  float* out = (float*)d_out;

  char* base = (char*)d_ws;
  size_t off = 0;
  auto alloc = [&](size_t bytes) -> char* {
    char* p = base + off;
    off += (bytes + 255) & ~(size_t)255;
    return p;
  };
  float* dinv  = (float*)alloc(N_NODES * 4);
  int*   cur   = (int*)  alloc(N_NODES * 4);
  int*   mcnt  = (int*)  alloc(N_NODES * 4);
  int*   csrc  = (int*)  alloc((size_t)N_NODES * CAP * 4);
  float* cnorm = (float*)alloc((size_t)N_NODES * CAP * 4);
  float* p1c   = (float*)alloc(192 * 128 * 4);
  float* p2c   = (float*)alloc(128 * 64 * 4);
  float* pb1   = (float*)alloc(128 * 4);
  const size_t BIG = (size_t)80000 * 192;
  float* h1 = (float*)alloc(BIG * 4);
  float* ah = (float*)alloc(BIG * 4);

  hipMemsetAsync(cur, 0, N_NODES * 4, stream);
  k_fillfix<<<625, 256, 0, stream>>>(EI, EW, cur, csrc, cnorm);
  k_degpad<<<2500, 256, 0, stream>>>(cur, csrc, cnorm, dinv, mcnt);
  // wnorm (blocks 0..2499) + weight pack (blocks 2500..2628) in one dispatch
  k_wnormpack<<<2629, 256, 0, stream>>>(cur, csrc, dinv, cnorm, TC1W, TC2W, TC1B, p1c, p2c, pb1);

  // layer 1 (agg + W1 + relu), t=9..11 fused
  k_aggg1<<<20000, 256, 0, stream>>>(X, dinv, mcnt, csrc, cnorm, W1, B1, h1);
  // layer 2 aggregation: merged 3-t3 single pass, readlane broadcast (round-0 proven)
  k_agg3m<<<20000, 256, 0, stream>>>(h1, dinv, mcnt, csrc, cnorm, ah);
  // fused W2-GEMM + conv1 + conv2 + out: v3, weights from global, DS-pressure halved
  k_fused<<<2500, 256, 0, stream>>>(ah, W2, B2, p1c, pb1, p2c, TC2B, OW, OB, out);
}

// Round 3
// 412.658 us; speedup vs baseline: 2.1753x; 2.1753x over previous
//
#include <hip/hip_runtime.h>

#define N_NODES 10000
#define EDGES   160000
#define BATCH   8
#define TT      12
#define HID     64
#define CAP     64       // fixed edge-slot capacity per node (avg deg 16, P(deg>64) ~ 0)

// ---------------- CSR build (fixed-capacity, no scan) ----------------

// fill fixed-cap lists with raw weights; cursor counts per node
__global__ __launch_bounds__(256) void k_fillfix(const int* __restrict__ ei,
                                                 const float* __restrict__ ew,
                                                 int* __restrict__ cur,
                                                 int* __restrict__ csrc,
                                                 float* __restrict__ cnorm) {
  int g = blockIdx.x * 256 + threadIdx.x;
  if (g < EDGES) {
    int s = ei[g], d = ei[EDGES + g];
    int slot = atomicAdd(&cur[d], 1);
    csrc[d * CAP + slot]  = s;
    cnorm[d * CAP + slot] = ew[g];
  }
}

// wave per node: zero pad slots cnt..m (m = pad8(cnt)), deg = 1 + sum(real w), dinv, mcnt
__global__ __launch_bounds__(256) void k_degpad(const int* __restrict__ cur,
                                                int* __restrict__ csrc,
                                                float* __restrict__ cnorm,
                                                float* __restrict__ dinv,
                                                int* __restrict__ mcnt) {
  int n = blockIdx.x * 4 + (threadIdx.x >> 6);
  int lane = threadIdx.x & 63;
  int cnt = cur[n];
  int m = (cnt + 7) & ~7;
  int base = n * CAP;
  if (lane >= cnt && lane < m) { csrc[base + lane] = 0; cnorm[base + lane] = 0.0f; }
  float s = (lane < cnt) ? cnorm[base + lane] : 0.0f;
  #pragma unroll
  for (int off = 32; off > 0; off >>= 1) s += __shfl_xor(s, off, 64);
  if (lane == 0) {
    dinv[n] = 1.0f / sqrtf(s + 1.0f);
    mcnt[n] = m;
  }
}

// merged: blocks 0..2499 = wnorm (cnorm[e] *= dinv[src]*dinv[n]); blocks 2500.. = weight pack
//  p1c [192][128]: row kk: t3=kk>>6, i=kk&63; col: half=col>>6 (t'=10+half), o=col&63
//  p2c [128][64]:  row kk: g=kk>>6 (t1 half), i=kk&63
//  pb1 [128] = tc1_b duplicated
__global__ __launch_bounds__(256) void k_wnormpack(const int* __restrict__ cur,
                                                   const int* __restrict__ csrc,
                                                   const float* __restrict__ dinv,
                                                   float* __restrict__ cnorm,
                                                   const float* __restrict__ tc1w,
                                                   const float* __restrict__ tc2w,
                                                   const float* __restrict__ tc1b,
                                                   float* __restrict__ p1c,
                                                   float* __restrict__ p2c,
                                                   float* __restrict__ pb1) {
  if (blockIdx.x < 2500) {
    int n = blockIdx.x * 4 + (threadIdx.x >> 6);
    int lane = threadIdx.x & 63;
    int cnt = cur[n];
    int m = (cnt + 7) & ~7;
    if (lane < m) {
      int idx = n * CAP + lane;
      cnorm[idx] = cnorm[idx] * dinv[csrc[idx]] * dinv[n];
    }
  } else {
    int g = (blockIdx.x - 2500) * 256 + threadIdx.x;
    if (g < 24576) {
      int kk = g >> 7, col = g & 127;
      int t3 = kk >> 6, i = kk & 63;
      int half = col >> 6, o = col & 63;
      float v;
      if (half == 0) v = tc1w[o * 192 + i * 3 + t3];
      else           v = (t3 == 0) ? 0.0f : tc1w[o * 192 + i * 3 + (t3 - 1)];
      p1c[g] = v;
    } else if (g < 24576 + 8192) {
      int r = g - 24576;
      int kk = r >> 6, o = r & 63;
      int gk = kk >> 6, i = kk & 63;
      p2c[r] = tc2w[o * 192 + i * 3 + gk];
    } else if (g < 24576 + 8192 + 128) {
      int r = g - 24576 - 8192;
      pb1[r] = tc1b[r & 63];
    }
  }
}

// ---------------- GCN layer 1: fused agg(X) @ W1 + b1, relu ----------------
// h1 row layout PACKED for the fused gather: floats [0..128) = interleaved (t0[c], t1[c])
// pairs at 2c/2c+1; floats [128..192) = t2[c]. One float2 + one float load per edge
// in the gather instead of three scalar loads.

__global__ __launch_bounds__(256) void k_aggg1(const float* __restrict__ X,
                                               const float* __restrict__ dinv,
                                               const int* __restrict__ mcnt,
                                               const int* __restrict__ csrc,
                                               const float* __restrict__ cnorm,
                                               const float* __restrict__ W1,
                                               const float* __restrict__ b1,
                                               float* __restrict__ h1) {
  int b = blockIdx.x & 7;                    // batch -> XCD affinity
  int grp = blockIdx.x >> 3;                 // 0..2499
  int n = grp * 4 + (threadIdx.x >> 6);
  int lane = threadIdx.x & 63;
  const float2* x0 = (const float2*)(X + (size_t)(b * TT + 9)  * N_NODES * 2);
  const float2* x1 = (const float2*)(X + (size_t)(b * TT + 10) * N_NODES * 2);
  const float2* x2 = (const float2*)(X + (size_t)(b * TT + 11) * N_NODES * 2);
  float a0x = 0.f, a0y = 0.f, a1x = 0.f, a1y = 0.f, a2x = 0.f, a2y = 0.f;
  int m = mcnt[n];
  if (lane < m) {                            // pads have w=0 so they contribute 0 anyway
    int idx = n * CAP + lane;
    float w = cnorm[idx];
    int s = csrc[idx];
    float2 s0 = x0[s], s1 = x1[s], s2v = x2[s];
    a0x = w * s0.x;  a0y = w * s0.y;
    a1x = w * s1.x;  a1y = w * s1.y;
    a2x = w * s2v.x; a2y = w * s2v.y;
  }
  if (lane == 0) {  // self-loop term
    float di = dinv[n];
    float sd = di * di;
    float2 v0 = x0[n], v1 = x1[n], v2 = x2[n];
    a0x += sd * v0.x; a0y += sd * v0.y;
    a1x += sd * v1.x; a1y += sd * v1.y;
    a2x += sd * v2.x; a2y += sd * v2.y;
  }
  #pragma unroll
  for (int off = 32; off > 0; off >>= 1) {
    a0x += __shfl_xor(a0x, off, 64);
    a0y += __shfl_xor(a0y, off, 64);
    a1x += __shfl_xor(a1x, off, 64);
    a1y += __shfl_xor(a1y, off, 64);
    a2x += __shfl_xor(a2x, off, 64);
    a2y += __shfl_xor(a2y, off, 64);
  }
  int c = lane;
  float w0 = W1[c], w1 = W1[64 + c], bc = b1[c];
  float r0 = fmaxf(a0x * w0 + a0y * w1 + bc, 0.0f);
  float r1 = fmaxf(a1x * w0 + a1y * w1 + bc, 0.0f);
  float r2 = fmaxf(a2x * w0 + a2y * w1 + bc, 0.0f);
  size_t ob = ((size_t)(b * N_NODES + n)) * 192;
  *(float2*)&h1[ob + 2 * c] = make_float2(r0, r1);   // 512B contiguous per wave
  h1[ob + 128 + c] = r2;                             // 256B contiguous per wave
}

// ---------------- fused gather + epilogue v4 ----------------
// Phase 0: each wave gathers 8 nodes' layer-2 aggregation (verbatim k_agg3m inner loop,
// readlane broadcast, packed-float2 h1 rows) straight into the As LDS tile -> the ah
// global round-trip (61MB write + 61MB read) and the whole k_agg3m dispatch disappear.
// Phases 1-3 = FROZEN v2 structure (LDS-staged Ws chunks, strides 196/68/132).
// LDS 59,392B -> 2 blocks/CU (8 waves/CU); DS-throughput-bound phases tolerate this.
__global__ __launch_bounds__(256, 2) void k_fused(const float* __restrict__ h1,
                                                  const float* __restrict__ dinv,
                                                  const int* __restrict__ mcnt,
                                                  const int* __restrict__ csrc,
                                                  const float* __restrict__ cnorm,
                                                  const float* __restrict__ W2,
                                                  const float* __restrict__ b2,
                                                  const float* __restrict__ p1c,
                                                  const float* __restrict__ pb1,
                                                  const float* __restrict__ p2c,
                                                  const float* __restrict__ tc2b,
                                                  const float* __restrict__ ow,
                                                  const float* __restrict__ obp,
                                                  float* __restrict__ out) {
  __shared__ __align__(16) float smem[14848];    // 59,392 B
  float* spL = smem;                             // [32][196] = 6272
  float* As  = smem + 6272;                      // [96][68] = 6528 ; t1L [32][132] overlaps
  float* t1L = As;
  float* Ws  = smem + 6272 + 6528;               // 2048 floats (8 KB), shared chunk buffer
  int tid = threadIdx.x;
  int wave = tid >> 6, c = tid & 63;
  size_t nodeBase = (size_t)blockIdx.x * 32;     // in (b*N+n) units

  // ---- phase 0: gather-aggregate 8 nodes per wave into As rows [3j..3j+2]
  for (int jj = 0; jj < 8; jj++) {
    int j = wave * 8 + jj;
    int gn = (int)nodeBase + j;                  // 0..79999, wave-uniform
    int b = gn / 10000;
    int n = gn - b * 10000;
    const float* hb = h1 + (size_t)b * N_NODES * 192;
    int m = mcnt[n];                             // <= 64, multiple of 8
    int idx = n * CAP + c;
    int ic = (c < m) ? idx : n * CAP;
    int sv = csrc[ic] * 192;                     // float offset of source row
    float wf = (c < m) ? cnorm[idx] : 0.0f;
    int wb = __float_as_int(wf);
    float a0 = 0.f, a1 = 0.f, a2 = 0.f;
    for (int e = 0; e < m; e += 8) {
      #pragma unroll
      for (int u = 0; u < 8; u++) {
        int   off = __builtin_amdgcn_readlane(sv, e + u);
        float w   = __int_as_float(__builtin_amdgcn_readlane(wb, e + u));
        const float* p = hb + off;
        float2 v01 = *(const float2*)(p + 2 * c);
        a0 += w * v01.x;
        a1 += w * v01.y;
        a2 += w * p[128 + c];
      }
    }
    float di = dinv[n];
    float s2 = di * di;
    const float* sr = hb + (size_t)n * 192;
    float2 s01 = *(const float2*)(sr + 2 * c);
    a0 += s2 * s01.x;
    a1 += s2 * s01.y;
    a2 += s2 * sr[128 + c];
    As[(3 * j + 0) * 68 + c] = a0;
    As[(3 * j + 1) * 68 + c] = a1;
    As[(3 * j + 2) * 68 + c] = a2;
  }
  __syncthreads();

  // ---- phase 1: sp = relu(As[96x64] @ W2[64x64] + b2) -> spL[n][t3*64+c]
  {
    int ty = tid >> 4, tx = tid & 15;            // rows 6ty+i, cols 4tx+j
    float acc[6][4] = {{0.f}};
    for (int k0 = 0; k0 < 64; k0 += 32) {
      #pragma unroll
      for (int rep = 0; rep < 2; rep++) {        // Ws: [32][64] chunk of W2
        int idx = rep * 256 + tid;
        int kk = idx >> 4, c4 = (idx & 15) * 4;
        *(float4*)&Ws[kk * 64 + c4] = *(const float4*)(W2 + (size_t)(k0 + kk) * 64 + c4);
      }
      __syncthreads();
      #pragma unroll
      for (int k = 0; k < 32; k += 4) {
        float4 a[6], w[4];
        #pragma unroll
        for (int i = 0; i < 6; i++) a[i] = *(const float4*)&As[(6 * ty + i) * 68 + k0 + k];
        #pragma unroll
        for (int kk = 0; kk < 4; kk++) w[kk] = *(const float4*)&Ws[(k + kk) * 64 + 4 * tx];
        #pragma unroll
        for (int i = 0; i < 6; i++) {
          float av[4] = {a[i].x, a[i].y, a[i].z, a[i].w};
          #pragma unroll
          for (int kk = 0; kk < 4; kk++) {
            acc[i][0] += av[kk] * w[kk].x;
            acc[i][1] += av[kk] * w[kk].y;
            acc[i][2] += av[kk] * w[kk].z;
            acc[i][3] += av[kk] * w[kk].w;
          }
        }
      }
      __syncthreads();
    }
    float4 bv = *(const float4*)(b2 + 4 * tx);
    #pragma unroll
    for (int i = 0; i < 6; i++) {
      int m = 6 * ty + i;
      int n = m / 3, t3 = m % 3;
      float4 o;
      o.x = fmaxf(acc[i][0] + bv.x, 0.0f);
      o.y = fmaxf(acc[i][1] + bv.y, 0.0f);
      o.z = fmaxf(acc[i][2] + bv.z, 0.0f);
      o.w = fmaxf(acc[i][3] + bv.w, 0.0f);
      *(float4*)&spL[n * 196 + t3 * 64 + 4 * tx] = o;
    }
  }
  __syncthreads();                               // As dead after this point

  // ---- phase 2: t1 = relu(spL[32x192] @ p1c[192x128] + pb1) -> t1L[32][132]
  {
    int ty = tid >> 5, tx = tid & 31;            // rows 4ty+i, cols 4tx+j
    float acc[4][4] = {{0.f}};
    for (int c12 = 0; c12 < 12; c12++) {
      #pragma unroll
      for (int rep = 0; rep < 2; rep++) {        // Ws: [16][128] chunk of p1c
        int idx = rep * 256 + tid;
        int kk = idx >> 5, c4 = (idx & 31) * 4;
        *(float4*)&Ws[kk * 128 + c4] = *(const float4*)(p1c + (size_t)(c12 * 16 + kk) * 128 + c4);
      }
      __syncthreads();
      int kbase = c12 * 16;
      #pragma unroll
      for (int k = 0; k < 16; k += 4) {
        float4 a[4], w[4];
        #pragma unroll
        for (int i = 0; i < 4; i++) a[i] = *(const float4*)&spL[(4 * ty + i) * 196 + kbase + k];
        #pragma unroll
        for (int kk = 0; kk < 4; kk++) w[kk] = *(const float4*)&Ws[(k + kk) * 128 + 4 * tx];
        #pragma unroll
        for (int i = 0; i < 4; i++) {
          float av[4] = {a[i].x, a[i].y, a[i].z, a[i].w};
          #pragma unroll
          for (int kk = 0; kk < 4; kk++) {
            acc[i][0] += av[kk] * w[kk].x;
            acc[i][1] += av[kk] * w[kk].y;
            acc[i][2] += av[kk] * w[kk].z;
            acc[i][3] += av[kk] * w[kk].w;
          }
        }
      }
      __syncthreads();
    }
    float4 bv = *(const float4*)(pb1 + 4 * tx);
    #pragma unroll
    for (int i = 0; i < 4; i++) {
      float4 o;
      o.x = fmaxf(acc[i][0] + bv.x, 0.0f);
      o.y = fmaxf(acc[i][1] + bv.y, 0.0f);
      o.z = fmaxf(acc[i][2] + bv.z, 0.0f);
      o.w = fmaxf(acc[i][3] + bv.w, 0.0f);
      *(float4*)&t1L[(4 * ty + i) * 132 + 4 * tx] = o;
    }
  }
  __syncthreads();

  // ---- phase 3: last = relu(t1L[32x128] @ p2c[128x64] + tc2b); out = last . ow + ob
  {
    int ty = tid >> 4, tx = tid & 15;            // rows 2ty+i, cols 4tx+j
    float acc[2][4] = {{0.f}};
    for (int c8 = 0; c8 < 8; c8++) {
      {                                          // Ws: [16][64] chunk of p2c
        int kk = tid >> 4, c4 = (tid & 15) * 4;
        *(float4*)&Ws[kk * 64 + c4] = *(const float4*)(p2c + (size_t)(c8 * 16 + kk) * 64 + c4);
      }
      __syncthreads();
      int kbase = c8 * 16;
      #pragma unroll
      for (int k = 0; k < 16; k += 4) {
        float4 a[2], w[4];
        #pragma unroll
        for (int i = 0; i < 2; i++) a[i] = *(const float4*)&t1L[(2 * ty + i) * 132 + kbase + k];
        #pragma unroll
        for (int kk = 0; kk < 4; kk++) w[kk] = *(const float4*)&Ws[(k + kk) * 64 + 4 * tx];
        #pragma unroll
        for (int i = 0; i < 2; i++) {
          float av[4] = {a[i].x, a[i].y, a[i].z, a[i].w};
          #pragma unroll
          for (int kk = 0; kk < 4; kk++) {
            acc[i][0] += av[kk] * w[kk].x;
            acc[i][1] += av[kk] * w[kk].y;
            acc[i][2] += av[kk] * w[kk].z;
            acc[i][3] += av[kk] * w[kk].w;
          }
        }
      }
      __syncthreads();
    }
    float4 bv = *(const float4*)(tc2b + 4 * tx);
    float4 o4 = *(const float4*)(ow + 4 * tx);
    float obv = obp[0];
    #pragma unroll
    for (int i = 0; i < 2; i++) {
      float v = fmaxf(acc[i][0] + bv.x, 0.0f) * o4.x
              + fmaxf(acc[i][1] + bv.y, 0.0f) * o4.y
              + fmaxf(acc[i][2] + bv.z, 0.0f) * o4.z
              + fmaxf(acc[i][3] + bv.w, 0.0f) * o4.w;
      v += __shfl_xor(v, 1, 64);
      v += __shfl_xor(v, 2, 64);
      v += __shfl_xor(v, 4, 64);
      v += __shfl_xor(v, 8, 64);
      if (tx == 0) out[nodeBase + 2 * ty + i] = v + obv;
    }
  }
}

// ---------------- launch ----------------

extern "C" void kernel_launch(void* const* d_in, const int* in_sizes, int n_in,
                              void* d_out, int out_size, void* d_ws, size_t ws_size,
                              hipStream_t stream) {
  const float* X    = (const float*)d_in[0];
  const int*   EI   = (const int*)  d_in[1];
  const float* EW   = (const float*)d_in[2];
  const float* W1   = (const float*)d_in[3];
  const float* B1   = (const float*)d_in[4];
  const float* W2   = (const float*)d_in[5];
  const float* B2   = (const float*)d_in[6];
  const float* TC1W = (const float*)d_in[7];
  const float* TC1B = (const float*)d_in[8];
  const float* TC2W = (const float*)d_in[9];
  const float* TC2B = (const float*)d_in[10];
  const float* OW   = (const float*)d_in[11];
  const float* OB   = (const float*)d_in[12];
  float* out = (float*)d_out;

  char* base = (char*)d_ws;
  size_t off = 0;
  auto alloc = [&](size_t bytes) -> char* {
    char* p = base + off;
    off += (bytes + 255) & ~(size_t)255;
    return p;
  };
  float* dinv  = (float*)alloc(N_NODES * 4);
  int*   cur   = (int*)  alloc(N_NODES * 4);
  int*   mcnt  = (int*)  alloc(N_NODES * 4);
  int*   csrc  = (int*)  alloc((size_t)N_NODES * CAP * 4);
  float* cnorm = (float*)alloc((size_t)N_NODES * CAP * 4);
  float* p1c   = (float*)alloc(192 * 128 * 4);
  float* p2c   = (float*)alloc(128 * 64 * 4);
  float* pb1   = (float*)alloc(128 * 4);
  const size_t BIG = (size_t)80000 * 192;
  float* h1 = (float*)alloc(BIG * 4);

  hipMemsetAsync(cur, 0, N_NODES * 4, stream);
  k_fillfix<<<625, 256, 0, stream>>>(EI, EW, cur, csrc, cnorm);
  k_degpad<<<2500, 256, 0, stream>>>(cur, csrc, cnorm, dinv, mcnt);
  // wnorm (blocks 0..2499) + weight pack (blocks 2500..2628) in one dispatch
  k_wnormpack<<<2629, 256, 0, stream>>>(cur, csrc, dinv, cnorm, TC1W, TC2W, TC1B, p1c, p2c, pb1);

  // layer 1 (agg + W1 + relu), t=9..11 fused; h1 rows packed (t0,t1 interleaved | t2)
  k_aggg1<<<20000, 256, 0, stream>>>(X, dinv, mcnt, csrc, cnorm, W1, B1, h1);
  // fused layer-2 gather + W2-GEMM + conv1 + conv2 + out (ah round-trip eliminated)
  k_fused<<<2500, 256, 0, stream>>>(h1, dinv, mcnt, csrc, cnorm,
                                    W2, B2, p1c, pb1, p2c, TC2B, OW, OB, out);
}

// Round 4
// 377.591 us; speedup vs baseline: 2.3773x; 1.0929x over previous
//
#include <hip/hip_runtime.h>

#define N_NODES 10000
#define EDGES   160000
#define BATCH   8
#define TT      12
#define HID     64
#define CAP     64       // fixed edge-slot capacity per node (avg deg 16, P(deg>64) ~ 0)

// ---------------- CSR build (fixed-capacity, no scan) ----------------

// fill fixed-cap lists with raw weights; cursor counts per node
__global__ __launch_bounds__(256) void k_fillfix(const int* __restrict__ ei,
                                                 const float* __restrict__ ew,
                                                 int* __restrict__ cur,
                                                 int* __restrict__ csrc,
                                                 float* __restrict__ cnorm) {
  int g = blockIdx.x * 256 + threadIdx.x;
  if (g < EDGES) {
    int s = ei[g], d = ei[EDGES + g];
    int slot = atomicAdd(&cur[d], 1);
    csrc[d * CAP + slot]  = s;
    cnorm[d * CAP + slot] = ew[g];
  }
}

// wave per node: zero pad slots cnt..m (m = pad8(cnt)), deg = 1 + sum(real w), dinv, mcnt
__global__ __launch_bounds__(256) void k_degpad(const int* __restrict__ cur,
                                                int* __restrict__ csrc,
                                                float* __restrict__ cnorm,
                                                float* __restrict__ dinv,
                                                int* __restrict__ mcnt) {
  int n = blockIdx.x * 4 + (threadIdx.x >> 6);
  int lane = threadIdx.x & 63;
  int cnt = cur[n];
  int m = (cnt + 7) & ~7;
  int base = n * CAP;
  if (lane >= cnt && lane < m) { csrc[base + lane] = 0; cnorm[base + lane] = 0.0f; }
  float s = (lane < cnt) ? cnorm[base + lane] : 0.0f;
  #pragma unroll
  for (int off = 32; off > 0; off >>= 1) s += __shfl_xor(s, off, 64);
  if (lane == 0) {
    dinv[n] = 1.0f / sqrtf(s + 1.0f);
    mcnt[n] = m;
  }
}

// merged: blocks 0..2499 = wnorm (cnorm[e] *= dinv[src]*dinv[n]); blocks 2500.. = weight pack
//  p1c [192][128]: row kk: t3=kk>>6, i=kk&63; col: half=col>>6 (t'=10+half), o=col&63
//  p2c [128][64]:  row kk: g=kk>>6 (t1 half), i=kk&63
//  pb1 [128] = tc1_b duplicated
__global__ __launch_bounds__(256) void k_wnormpack(const int* __restrict__ cur,
                                                   const int* __restrict__ csrc,
                                                   const float* __restrict__ dinv,
                                                   float* __restrict__ cnorm,
                                                   const float* __restrict__ tc1w,
                                                   const float* __restrict__ tc2w,
                                                   const float* __restrict__ tc1b,
                                                   float* __restrict__ p1c,
                                                   float* __restrict__ p2c,
                                                   float* __restrict__ pb1) {
  if (blockIdx.x < 2500) {
    int n = blockIdx.x * 4 + (threadIdx.x >> 6);
    int lane = threadIdx.x & 63;
    int cnt = cur[n];
    int m = (cnt + 7) & ~7;
    if (lane < m) {
      int idx = n * CAP + lane;
      cnorm[idx] = cnorm[idx] * dinv[csrc[idx]] * dinv[n];
    }
  } else {
    int g = (blockIdx.x - 2500) * 256 + threadIdx.x;
    if (g < 24576) {
      int kk = g >> 7, col = g & 127;
      int t3 = kk >> 6, i = kk & 63;
      int half = col >> 6, o = col & 63;
      float v;
      if (half == 0) v = tc1w[o * 192 + i * 3 + t3];
      else           v = (t3 == 0) ? 0.0f : tc1w[o * 192 + i * 3 + (t3 - 1)];
      p1c[g] = v;
    } else if (g < 24576 + 8192) {
      int r = g - 24576;
      int kk = r >> 6, o = r & 63;
      int gk = kk >> 6, i = kk & 63;
      p2c[r] = tc2w[o * 192 + i * 3 + gk];
    } else if (g < 24576 + 8192 + 128) {
      int r = g - 24576 - 8192;
      pb1[r] = tc1b[r & 63];
    }
  }
}

// ---------------- GCN layer 1: fused agg(X) @ W1 + b1, relu ----------------
// h1 row layout PACKED for the gather: floats [0..128) = interleaved (t0[c], t1[c])
// pairs at 2c/2c+1; floats [128..192) = t2[c]. One float2 + one float load per edge
// per batch in the gather instead of three scalar loads.

__global__ __launch_bounds__(256) void k_aggg1(const float* __restrict__ X,
                                               const float* __restrict__ dinv,
                                               const int* __restrict__ mcnt,
                                               const int* __restrict__ csrc,
                                               const float* __restrict__ cnorm,
                                               const float* __restrict__ W1,
                                               const float* __restrict__ b1,
                                               float* __restrict__ h1) {
  int b = blockIdx.x & 7;                    // batch -> XCD affinity
  int grp = blockIdx.x >> 3;                 // 0..2499
  int n = grp * 4 + (threadIdx.x >> 6);
  int lane = threadIdx.x & 63;
  const float2* x0 = (const float2*)(X + (size_t)(b * TT + 9)  * N_NODES * 2);
  const float2* x1 = (const float2*)(X + (size_t)(b * TT + 10) * N_NODES * 2);
  const float2* x2 = (const float2*)(X + (size_t)(b * TT + 11) * N_NODES * 2);
  float a0x = 0.f, a0y = 0.f, a1x = 0.f, a1y = 0.f, a2x = 0.f, a2y = 0.f;
  int m = mcnt[n];
  if (lane < m) {                            // pads have w=0 so they contribute 0 anyway
    int idx = n * CAP + lane;
    float w = cnorm[idx];
    int s = csrc[idx];
    float2 s0 = x0[s], s1 = x1[s], s2v = x2[s];
    a0x = w * s0.x;  a0y = w * s0.y;
    a1x = w * s1.x;  a1y = w * s1.y;
    a2x = w * s2v.x; a2y = w * s2v.y;
  }
  if (lane == 0) {  // self-loop term
    float di = dinv[n];
    float sd = di * di;
    float2 v0 = x0[n], v1 = x1[n], v2 = x2[n];
    a0x += sd * v0.x; a0y += sd * v0.y;
    a1x += sd * v1.x; a1y += sd * v1.y;
    a2x += sd * v2.x; a2y += sd * v2.y;
  }
  #pragma unroll
  for (int off = 32; off > 0; off >>= 1) {
    a0x += __shfl_xor(a0x, off, 64);
    a0y += __shfl_xor(a0y, off, 64);
    a1x += __shfl_xor(a1x, off, 64);
    a1y += __shfl_xor(a1y, off, 64);
    a2x += __shfl_xor(a2x, off, 64);
    a2y += __shfl_xor(a2y, off, 64);
  }
  int c = lane;
  float w0 = W1[c], w1 = W1[64 + c], bc = b1[c];
  float r0 = fmaxf(a0x * w0 + a0y * w1 + bc, 0.0f);
  float r1 = fmaxf(a1x * w0 + a1y * w1 + bc, 0.0f);
  float r2 = fmaxf(a2x * w0 + a2y * w1 + bc, 0.0f);
  size_t ob = ((size_t)(b * N_NODES + n)) * 192;
  *(float2*)&h1[ob + 2 * c] = make_float2(r0, r1);   // 512B contiguous per wave
  h1[ob + 128 + c] = r2;                             // 256B contiguous per wave
}

// ---------------- GCN layer 2 aggregation: 4 batches per wave ----------------
// All 8 batches share the SAME graph, so metadata (mcnt/csrc/cnorm) and the per-edge
// readlane broadcasts are amortized over 4 batches per wave. Per edge: 2 readlane +
// 8 loads (4x packed float2+float) + 12 FMA, vs 4x(2 readlane + 3 loads + 3 FMA)
// in the old per-batch form. Wave count 80000 -> 20000; loads-in-flight/wave ~2.7x.
// Output ah stays in the plain [t3*64+c] layout k_fused consumes.
__global__ __launch_bounds__(256) void k_agg3q(const float* __restrict__ h1,
                                               const float* __restrict__ dinv,
                                               const int* __restrict__ mcnt,
                                               const int* __restrict__ csrc,
                                               const float* __restrict__ cnorm,
                                               float* __restrict__ ah) {
  int bq = blockIdx.x & 1;                   // 0 -> batches 0..3, 1 -> batches 4..7
  int grp = blockIdx.x >> 1;                 // 0..2499
  int n = grp * 4 + (threadIdx.x >> 6);
  int c = threadIdx.x & 63;
  const float* hb[4];
  #pragma unroll
  for (int bi = 0; bi < 4; bi++)
    hb[bi] = h1 + (size_t)(bq * 4 + bi) * N_NODES * 192;

  int m = mcnt[n];                           // <= 64, multiple of 8
  int idx = n * CAP + c;
  int ic = (c < m) ? idx : n * CAP;
  int sv = csrc[ic] * 192;                   // float offset of source row
  float wf = (c < m) ? cnorm[idx] : 0.0f;
  int wb = __float_as_int(wf);

  float a00 = 0.f, a01 = 0.f, a02 = 0.f;
  float a10 = 0.f, a11 = 0.f, a12 = 0.f;
  float a20 = 0.f, a21 = 0.f, a22 = 0.f;
  float a30 = 0.f, a31 = 0.f, a32 = 0.f;

  for (int e = 0; e < m; e += 4) {           // 4-edge groups: 32 loads in flight
    #pragma unroll
    for (int u = 0; u < 4; u++) {
      int   off = __builtin_amdgcn_readlane(sv, e + u);
      float w   = __int_as_float(__builtin_amdgcn_readlane(wb, e + u));
      const float* p0 = hb[0] + off;
      const float* p1 = hb[1] + off;
      const float* p2 = hb[2] + off;
      const float* p3 = hb[3] + off;
      float2 v0 = *(const float2*)(p0 + 2 * c);
      float2 v1 = *(const float2*)(p1 + 2 * c);
      float2 v2 = *(const float2*)(p2 + 2 * c);
      float2 v3 = *(const float2*)(p3 + 2 * c);
      float t0 = p0[128 + c];
      float t1 = p1[128 + c];
      float t2 = p2[128 + c];
      float t3 = p3[128 + c];
      a00 += w * v0.x;  a01 += w * v0.y;  a02 += w * t0;
      a10 += w * v1.x;  a11 += w * v1.y;  a12 += w * t1;
      a20 += w * v2.x;  a21 += w * v2.y;  a22 += w * t2;
      a30 += w * v3.x;  a31 += w * v3.y;  a32 += w * t3;
    }
  }

  float di = dinv[n];
  float s2 = di * di;
  int so = n * 192;
  {
    const float* sr = hb[0] + so;
    float2 s01 = *(const float2*)(sr + 2 * c);
    size_t ob = ((size_t)((bq * 4 + 0) * N_NODES + n)) * 192 + c;
    ah[ob]       = a00 + s2 * s01.x;
    ah[ob + 64]  = a01 + s2 * s01.y;
    ah[ob + 128] = a02 + s2 * sr[128 + c];
  }
  {
    const float* sr = hb[1] + so;
    float2 s01 = *(const float2*)(sr + 2 * c);
    size_t ob = ((size_t)((bq * 4 + 1) * N_NODES + n)) * 192 + c;
    ah[ob]       = a10 + s2 * s01.x;
    ah[ob + 64]  = a11 + s2 * s01.y;
    ah[ob + 128] = a12 + s2 * sr[128 + c];
  }
  {
    const float* sr = hb[2] + so;
    float2 s01 = *(const float2*)(sr + 2 * c);
    size_t ob = ((size_t)((bq * 4 + 2) * N_NODES + n)) * 192 + c;
    ah[ob]       = a20 + s2 * s01.x;
    ah[ob + 64]  = a21 + s2 * s01.y;
    ah[ob + 128] = a22 + s2 * sr[128 + c];
  }
  {
    const float* sr = hb[3] + so;
    float2 s01 = *(const float2*)(sr + 2 * c);
    size_t ob = ((size_t)((bq * 4 + 3) * N_NODES + n)) * 192 + c;
    ah[ob]       = a30 + s2 * s01.x;
    ah[ob + 64]  = a31 + s2 * s01.y;
    ah[ob + 128] = a32 + s2 * sr[128 + c];
  }
}

// ---------------- fused epilogue v2 (FROZEN; measured 132-137 us): 32 nodes/block ----------------
// LDS 50,176 B -> 3 blocks/CU. Row-major [m][k] tiles with strides 36/196/132;
// all inner-loop LDS reads are float4 along k (b128), A-fragment reads are 2-4-address
// wave broadcasts -> no bank conflicts in the hot loops.
__global__ __launch_bounds__(256, 3) void k_fused(const float* __restrict__ ah,
                                                  const float* __restrict__ W2,
                                                  const float* __restrict__ b2,
                                                  const float* __restrict__ p1c,
                                                  const float* __restrict__ pb1,
                                                  const float* __restrict__ p2c,
                                                  const float* __restrict__ tc2b,
                                                  const float* __restrict__ ow,
                                                  const float* __restrict__ obp,
                                                  float* __restrict__ out) {
  __shared__ __align__(16) float smem[12544];    // 50,176 B
  float* spL = smem;                             // [32][196] = 6272
  float* ovl = smem + 6272;                      // As [96][36]=3456  |  t1L [32][132]=4224
  float* Ws  = smem + 6272 + 4224;               // 2048 floats (8 KB), shared chunk buffer
  float* As  = ovl;
  float* t1L = ovl;
  int tid = threadIdx.x;
  size_t nodeBase = (size_t)blockIdx.x * 32;     // in (b*N+n) units
  const float* A = ah + nodeBase * 192;          // 96 rows (n,t3) x 64, row-major

  // ---- phase 1: sp = relu(A[96x64] @ W2[64x64] + b2) -> spL[n][t3*64+c]
  {
    int ty = tid >> 4, tx = tid & 15;            // rows 6ty+i, cols 4tx+j
    float acc[6][4] = {{0.f}};
    for (int k0 = 0; k0 < 64; k0 += 32) {
      #pragma unroll
      for (int rep = 0; rep < 3; rep++) {        // As: 768 float4
        int idx = rep * 256 + tid;
        int m = idx >> 3, q4 = (idx & 7) * 4;
        *(float4*)&As[m * 36 + q4] = *(const float4*)(A + m * 64 + k0 + q4);
      }
      #pragma unroll
      for (int rep = 0; rep < 2; rep++) {        // Ws: [32][64] chunk of W2
        int idx = rep * 256 + tid;
        int kk = idx >> 4, c4 = (idx & 15) * 4;
        *(float4*)&Ws[kk * 64 + c4] = *(const float4*)(W2 + (size_t)(k0 + kk) * 64 + c4);
      }
      __syncthreads();
      #pragma unroll
      for (int k = 0; k < 32; k += 4) {
        float4 a[6], w[4];
        #pragma unroll
        for (int i = 0; i < 6; i++) a[i] = *(const float4*)&As[(6 * ty + i) * 36 + k];
        #pragma unroll
        for (int kk = 0; kk < 4; kk++) w[kk] = *(const float4*)&Ws[(k + kk) * 64 + 4 * tx];
        #pragma unroll
        for (int i = 0; i < 6; i++) {
          float av[4] = {a[i].x, a[i].y, a[i].z, a[i].w};
          #pragma unroll
          for (int kk = 0; kk < 4; kk++) {
            acc[i][0] += av[kk] * w[kk].x;
            acc[i][1] += av[kk] * w[kk].y;
            acc[i][2] += av[kk] * w[kk].z;
            acc[i][3] += av[kk] * w[kk].w;
          }
        }
      }
      __syncthreads();
    }
    float4 bv = *(const float4*)(b2 + 4 * tx);
    #pragma unroll
    for (int i = 0; i < 6; i++) {
      int m = 6 * ty + i;
      int n = m / 3, t3 = m % 3;
      float4 o;
      o.x = fmaxf(acc[i][0] + bv.x, 0.0f);
      o.y = fmaxf(acc[i][1] + bv.y, 0.0f);
      o.z = fmaxf(acc[i][2] + bv.z, 0.0f);
      o.w = fmaxf(acc[i][3] + bv.w, 0.0f);
      *(float4*)&spL[n * 196 + t3 * 64 + 4 * tx] = o;
    }
  }
  __syncthreads();

  // ---- phase 2: t1 = relu(spL[32x192] @ p1c[192x128] + pb1) -> t1L[32][132]
  {
    int ty = tid >> 5, tx = tid & 31;            // rows 4ty+i, cols 4tx+j
    float acc[4][4] = {{0.f}};
    for (int c12 = 0; c12 < 12; c12++) {
      #pragma unroll
      for (int rep = 0; rep < 2; rep++) {        // Ws: [16][128] chunk of p1c
        int idx = rep * 256 + tid;
        int kk = idx >> 5, c4 = (idx & 31) * 4;
        *(float4*)&Ws[kk * 128 + c4] = *(const float4*)(p1c + (size_t)(c12 * 16 + kk) * 128 + c4);
      }
      __syncthreads();
      int kbase = c12 * 16;
      #pragma unroll
      for (int k = 0; k < 16; k += 4) {
        float4 a[4], w[4];
        #pragma unroll
        for (int i = 0; i < 4; i++) a[i] = *(const float4*)&spL[(4 * ty + i) * 196 + kbase + k];
        #pragma unroll
        for (int kk = 0; kk < 4; kk++) w[kk] = *(const float4*)&Ws[(k + kk) * 128 + 4 * tx];
        #pragma unroll
        for (int i = 0; i < 4; i++) {
          float av[4] = {a[i].x, a[i].y, a[i].z, a[i].w};
          #pragma unroll
          for (int kk = 0; kk < 4; kk++) {
            acc[i][0] += av[kk] * w[kk].x;
            acc[i][1] += av[kk] * w[kk].y;
            acc[i][2] += av[kk] * w[kk].z;
            acc[i][3] += av[kk] * w[kk].w;
          }
        }
      }
      __syncthreads();
    }
    float4 bv = *(const float4*)(pb1 + 4 * tx);
    #pragma unroll
    for (int i = 0; i < 4; i++) {
      float4 o;
      o.x = fmaxf(acc[i][0] + bv.x, 0.0f);
      o.y = fmaxf(acc[i][1] + bv.y, 0.0f);
      o.z = fmaxf(acc[i][2] + bv.z, 0.0f);
      o.w = fmaxf(acc[i][3] + bv.w, 0.0f);
      *(float4*)&t1L[(4 * ty + i) * 132 + 4 * tx] = o;
    }
  }
  __syncthreads();

  // ---- phase 3: last = relu(t1L[32x128] @ p2c[128x64] + tc2b); out = last . ow + ob
  {
    int ty = tid >> 4, tx = tid & 15;            // rows 2ty+i, cols 4tx+j
    float acc[2][4] = {{0.f}};
    for (int c8 = 0; c8 < 8; c8++) {
      {                                          // Ws: [16][64] chunk of p2c
        int kk = tid >> 4, c4 = (tid & 15) * 4;
        *(float4*)&Ws[kk * 64 + c4] = *(const float4*)(p2c + (size_t)(c8 * 16 + kk) * 64 + c4);
      }
      __syncthreads();
      int kbase = c8 * 16;
      #pragma unroll
      for (int k = 0; k < 16; k += 4) {
        float4 a[2], w[4];
        #pragma unroll
        for (int i = 0; i < 2; i++) a[i] = *(const float4*)&t1L[(2 * ty + i) * 132 + kbase + k];
        #pragma unroll
        for (int kk = 0; kk < 4; kk++) w[kk] = *(const float4*)&Ws[(k + kk) * 64 + 4 * tx];
        #pragma unroll
        for (int i = 0; i < 2; i++) {
          float av[4] = {a[i].x, a[i].y, a[i].z, a[i].w};
          #pragma unroll
          for (int kk = 0; kk < 4; kk++) {
            acc[i][0] += av[kk] * w[kk].x;
            acc[i][1] += av[kk] * w[kk].y;
            acc[i][2] += av[kk] * w[kk].z;
            acc[i][3] += av[kk] * w[kk].w;
          }
        }
      }
      __syncthreads();
    }
    float4 bv = *(const float4*)(tc2b + 4 * tx);
    float4 o4 = *(const float4*)(ow + 4 * tx);
    float obv = obp[0];
    #pragma unroll
    for (int i = 0; i < 2; i++) {
      float v = fmaxf(acc[i][0] + bv.x, 0.0f) * o4.x
              + fmaxf(acc[i][1] + bv.y, 0.0f) * o4.y
              + fmaxf(acc[i][2] + bv.z, 0.0f) * o4.z
              + fmaxf(acc[i][3] + bv.w, 0.0f) * o4.w;
      v += __shfl_xor(v, 1, 64);
      v += __shfl_xor(v, 2, 64);
      v += __shfl_xor(v, 4, 64);
      v += __shfl_xor(v, 8, 64);
      if (tx == 0) out[nodeBase + 2 * ty + i] = v + obv;
    }
  }
}

// ---------------- launch ----------------

extern "C" void kernel_launch(void* const* d_in, const int* in_sizes, int n_in,
                              void* d_out, int out_size, void* d_ws, size_t ws_size,
                              hipStream_t stream) {
  const float* X    = (const float*)d_in[0];
  const int*   EI   = (const int*)  d_in[1];
  const float* EW   = (const float*)d_in[2];
  const float* W1   = (const float*)d_in[3];
  const float* B1   = (const float*)d_in[4];
  const float* W2   = (const float*)d_in[5];
  const float* B2   = (const float*)d_in[6];
  const float* TC1W = (const float*)d_in[7];
  const float* TC1B = (const float*)d_in[8];
  const float* TC2W = (const float*)d_in[9];
  const float* TC2B = (const float*)d_in[10];
  const float* OW   = (const float*)d_in[11];
  const float* OB   = (const float*)d_in[12];
  float* out = (float*)d_out;

  char* base = (char*)d_ws;
  size_t off = 0;
  auto alloc = [&](size_t bytes) -> char* {
    char* p = base + off;
    off += (bytes + 255) & ~(size_t)255;
    return p;
  };
  float* dinv  = (float*)alloc(N_NODES * 4);
  int*   cur   = (int*)  alloc(N_NODES * 4);
  int*   mcnt  = (int*)  alloc(N_NODES * 4);
  int*   csrc  = (int*)  alloc((size_t)N_NODES * CAP * 4);
  float* cnorm = (float*)alloc((size_t)N_NODES * CAP * 4);
  float* p1c   = (float*)alloc(192 * 128 * 4);
  float* p2c   = (float*)alloc(128 * 64 * 4);
  float* pb1   = (float*)alloc(128 * 4);
  const size_t BIG = (size_t)80000 * 192;
  float* h1 = (float*)alloc(BIG * 4);
  float* ah = (float*)alloc(BIG * 4);

  hipMemsetAsync(cur, 0, N_NODES * 4, stream);
  k_fillfix<<<625, 256, 0, stream>>>(EI, EW, cur, csrc, cnorm);
  k_degpad<<<2500, 256, 0, stream>>>(cur, csrc, cnorm, dinv, mcnt);
  // wnorm (blocks 0..2499) + weight pack (blocks 2500..2628) in one dispatch
  k_wnormpack<<<2629, 256, 0, stream>>>(cur, csrc, dinv, cnorm, TC1W, TC2W, TC1B, p1c, p2c, pb1);

  // layer 1 (agg + W1 + relu), t=9..11 fused; h1 rows packed (t0,t1 interleaved | t2)
  k_aggg1<<<20000, 256, 0, stream>>>(X, dinv, mcnt, csrc, cnorm, W1, B1, h1);
  // layer 2 aggregation: 4 batches/wave, shared-graph metadata amortized
  k_agg3q<<<5000, 256, 0, stream>>>(h1, dinv, mcnt, csrc, cnorm, ah);
  // fused W2-GEMM + conv1 + conv2 + out (32 nodes/block, LDS-staged weights) -- FROZEN
  k_fused<<<2500, 256, 0, stream>>>(ah, W2, B2, p1c, pb1, p2c, TC2B, OW, OB, out);
}

// Round 5
// 288.208 us; speedup vs baseline: 3.1145x; 1.3101x over previous
//
#include <hip/hip_runtime.h>
#include <hip/hip_fp16.h>

#define N_NODES 10000
#define EDGES   160000
#define BATCH   8
#define TT      12
#define HID     64
#define CAP     64       // fixed edge-slot capacity per node (avg deg 16, P(deg>64) ~ 0)

// ---------------- CSR build (fixed-capacity, no scan) ----------------

// fill fixed-cap lists with raw weights; cursor counts per node
__global__ __launch_bounds__(256) void k_fillfix(const int* __restrict__ ei,
                                                 const float* __restrict__ ew,
                                                 int* __restrict__ cur,
                                                 int* __restrict__ csrc,
                                                 float* __restrict__ cnorm) {
  int g = blockIdx.x * 256 + threadIdx.x;
  if (g < EDGES) {
    int s = ei[g], d = ei[EDGES + g];
    int slot = atomicAdd(&cur[d], 1);
    csrc[d * CAP + slot]  = s;
    cnorm[d * CAP + slot] = ew[g];
  }
}

// wave per node: zero pad slots cnt..m (m = pad8(cnt)), deg = 1 + sum(real w), dinv, mcnt
__global__ __launch_bounds__(256) void k_degpad(const int* __restrict__ cur,
                                                int* __restrict__ csrc,
                                                float* __restrict__ cnorm,
                                                float* __restrict__ dinv,
                                                int* __restrict__ mcnt) {
  int n = blockIdx.x * 4 + (threadIdx.x >> 6);
  int lane = threadIdx.x & 63;
  int cnt = cur[n];
  int m = (cnt + 7) & ~7;
  int base = n * CAP;
  if (lane >= cnt && lane < m) { csrc[base + lane] = 0; cnorm[base + lane] = 0.0f; }
  float s = (lane < cnt) ? cnorm[base + lane] : 0.0f;
  #pragma unroll
  for (int off = 32; off > 0; off >>= 1) s += __shfl_xor(s, off, 64);
  if (lane == 0) {
    dinv[n] = 1.0f / sqrtf(s + 1.0f);
    mcnt[n] = m;
  }
}

// merged: blocks 0..2499 = wnorm (cnorm[e] *= dinv[src]*dinv[n]); blocks 2500.. = weight pack
//  p1c [192][128]: row kk: t3=kk>>6, i=kk&63; col: half=col>>6 (t'=10+half), o=col&63
//  p2c [128][64]:  row kk: g=kk>>6 (t1 half), i=kk&63
//  pb1 [128] = tc1_b duplicated
__global__ __launch_bounds__(256) void k_wnormpack(const int* __restrict__ cur,
                                                   const int* __restrict__ csrc,
                                                   const float* __restrict__ dinv,
                                                   float* __restrict__ cnorm,
                                                   const float* __restrict__ tc1w,
                                                   const float* __restrict__ tc2w,
                                                   const float* __restrict__ tc1b,
                                                   float* __restrict__ p1c,
                                                   float* __restrict__ p2c,
                                                   float* __restrict__ pb1) {
  if (blockIdx.x < 2500) {
    int n = blockIdx.x * 4 + (threadIdx.x >> 6);
    int lane = threadIdx.x & 63;
    int cnt = cur[n];
    int m = (cnt + 7) & ~7;
    if (lane < m) {
      int idx = n * CAP + lane;
      cnorm[idx] = cnorm[idx] * dinv[csrc[idx]] * dinv[n];
    }
  } else {
    int g = (blockIdx.x - 2500) * 256 + threadIdx.x;
    if (g < 24576) {
      int kk = g >> 7, col = g & 127;
      int t3 = kk >> 6, i = kk & 63;
      int half = col >> 6, o = col & 63;
      float v;
      if (half == 0) v = tc1w[o * 192 + i * 3 + t3];
      else           v = (t3 == 0) ? 0.0f : tc1w[o * 192 + i * 3 + (t3 - 1)];
      p1c[g] = v;
    } else if (g < 24576 + 8192) {
      int r = g - 24576;
      int kk = r >> 6, o = r & 63;
      int gk = kk >> 6, i = kk & 63;
      p2c[r] = tc2w[o * 192 + i * 3 + gk];
    } else if (g < 24576 + 8192 + 128) {
      int r = g - 24576 - 8192;
      pb1[r] = tc1b[r & 63];
    }
  }
}

// ---------------- GCN layer 1: fused agg(X) @ W1 + b1, relu ----------------
// h1 is stored FP16 (accumulation stays fp32 everywhere): per-batch slab = 3.84MB
// <= 4MB XCD L2 -> the layer-2 gather becomes L2-resident. Row layout (ushort units):
// [0..128) = interleaved (t0[c],t1[c]) half2 at 2c; [128..192) = t2[c].

__global__ __launch_bounds__(256) void k_aggg1(const float* __restrict__ X,
                                               const float* __restrict__ dinv,
                                               const int* __restrict__ mcnt,
                                               const int* __restrict__ csrc,
                                               const float* __restrict__ cnorm,
                                               const float* __restrict__ W1,
                                               const float* __restrict__ b1,
                                               ushort* __restrict__ h1) {
  int b = blockIdx.x & 7;                    // batch -> XCD affinity
  int grp = blockIdx.x >> 3;                 // 0..2499
  int n = grp * 4 + (threadIdx.x >> 6);
  int lane = threadIdx.x & 63;
  const float2* x0 = (const float2*)(X + (size_t)(b * TT + 9)  * N_NODES * 2);
  const float2* x1 = (const float2*)(X + (size_t)(b * TT + 10) * N_NODES * 2);
  const float2* x2 = (const float2*)(X + (size_t)(b * TT + 11) * N_NODES * 2);
  float a0x = 0.f, a0y = 0.f, a1x = 0.f, a1y = 0.f, a2x = 0.f, a2y = 0.f;
  int m = mcnt[n];
  if (lane < m) {                            // pads have w=0 so they contribute 0 anyway
    int idx = n * CAP + lane;
    float w = cnorm[idx];
    int s = csrc[idx];
    float2 s0 = x0[s], s1 = x1[s], s2v = x2[s];
    a0x = w * s0.x;  a0y = w * s0.y;
    a1x = w * s1.x;  a1y = w * s1.y;
    a2x = w * s2v.x; a2y = w * s2v.y;
  }
  if (lane == 0) {  // self-loop term
    float di = dinv[n];
    float sd = di * di;
    float2 v0 = x0[n], v1 = x1[n], v2 = x2[n];
    a0x += sd * v0.x; a0y += sd * v0.y;
    a1x += sd * v1.x; a1y += sd * v1.y;
    a2x += sd * v2.x; a2y += sd * v2.y;
  }
  #pragma unroll
  for (int off = 32; off > 0; off >>= 1) {
    a0x += __shfl_xor(a0x, off, 64);
    a0y += __shfl_xor(a0y, off, 64);
    a1x += __shfl_xor(a1x, off, 64);
    a1y += __shfl_xor(a1y, off, 64);
    a2x += __shfl_xor(a2x, off, 64);
    a2y += __shfl_xor(a2y, off, 64);
  }
  int c = lane;
  float w0 = W1[c], w1 = W1[64 + c], bc = b1[c];
  float r0 = fmaxf(a0x * w0 + a0y * w1 + bc, 0.0f);
  float r1 = fmaxf(a1x * w0 + a1y * w1 + bc, 0.0f);
  float r2 = fmaxf(a2x * w0 + a2y * w1 + bc, 0.0f);
  ushort* row = h1 + ((size_t)(b * N_NODES + n)) * 192;
  *(__half2*)(row + 2 * c)  = __floats2half2_rn(r0, r1);   // 256B contiguous per wave
  *(__half*)(row + 128 + c) = __float2half_rn(r2);         // 128B contiguous per wave
}

// ---------------- GCN layer 2 aggregation: fp16 L2-resident gather ----------------
// Round-0 proven structure (1 batch/wave, batch->XCD affinity, readlane broadcast),
// data width halved: per edge 1 dword (half2 t0,t1) + 1 ushort (t2) load + 3 cvt.
// Per-XCD working set = one 3.84MB slab -> L2-resident after first touch.
// Output ah stays FP32 in the [t3*64+c] layout k_fused consumes (k_fused FROZEN).
__global__ __launch_bounds__(256) void k_agg3m16(const ushort* __restrict__ h1,
                                                 const float* __restrict__ dinv,
                                                 const int* __restrict__ mcnt,
                                                 const int* __restrict__ csrc,
                                                 const float* __restrict__ cnorm,
                                                 float* __restrict__ ah) {
  int b = blockIdx.x & 7;                    // batch -> XCD affinity
  int grp = blockIdx.x >> 3;                 // 0..2499
  int n = grp * 4 + (threadIdx.x >> 6);
  int c = threadIdx.x & 63;
  const ushort* hb = h1 + (size_t)b * N_NODES * 192;
  float acc0 = 0.f, acc1 = 0.f, acc2 = 0.f;
  int m = mcnt[n];                           // <= 64, multiple of 8
  int idx = n * CAP + c;
  int ic = (c < m) ? idx : n * CAP;
  int sv = csrc[ic] * 192;                   // ushort offset of source row
  float wf = (c < m) ? cnorm[idx] : 0.0f;
  int wb = __float_as_int(wf);
  for (int e = 0; e < m; e += 8) {
    #pragma unroll
    for (int u = 0; u < 8; u++) {
      int   off = __builtin_amdgcn_readlane(sv, e + u);
      float w   = __int_as_float(__builtin_amdgcn_readlane(wb, e + u));
      const ushort* p = hb + off;
      float2 f01 = __half22float2(*(const __half2*)(p + 2 * c));
      float  t2v = __half2float(*(const __half*)(p + 128 + c));
      acc0 += w * f01.x;
      acc1 += w * f01.y;
      acc2 += w * t2v;
    }
  }
  float di = dinv[n];
  float s2 = di * di;
  const ushort* sr = hb + (size_t)n * 192;
  float2 fs = __half22float2(*(const __half2*)(sr + 2 * c));
  float  fst = __half2float(*(const __half*)(sr + 128 + c));
  size_t ob = ((size_t)(b * N_NODES + n)) * 192 + c;
  ah[ob]       = acc0 + s2 * fs.x;
  ah[ob + 64]  = acc1 + s2 * fs.y;
  ah[ob + 128] = acc2 + s2 * fst;
}

// ---------------- fused epilogue v2 (FROZEN; measured 132-137 us): 32 nodes/block ----------------
// LDS 50,176 B -> 3 blocks/CU. Row-major [m][k] tiles with strides 36/196/132;
// all inner-loop LDS reads are float4 along k (b128), A-fragment reads are 2-4-address
// wave broadcasts -> no bank conflicts in the hot loops.
__global__ __launch_bounds__(256, 3) void k_fused(const float* __restrict__ ah,
                                                  const float* __restrict__ W2,
                                                  const float* __restrict__ b2,
                                                  const float* __restrict__ p1c,
                                                  const float* __restrict__ pb1,
                                                  const float* __restrict__ p2c,
                                                  const float* __restrict__ tc2b,
                                                  const float* __restrict__ ow,
                                                  const float* __restrict__ obp,
                                                  float* __restrict__ out) {
  __shared__ __align__(16) float smem[12544];    // 50,176 B
  float* spL = smem;                             // [32][196] = 6272
  float* ovl = smem + 6272;                      // As [96][36]=3456  |  t1L [32][132]=4224
  float* Ws  = smem + 6272 + 4224;               // 2048 floats (8 KB), shared chunk buffer
  float* As  = ovl;
  float* t1L = ovl;
  int tid = threadIdx.x;
  size_t nodeBase = (size_t)blockIdx.x * 32;     // in (b*N+n) units
  const float* A = ah + nodeBase * 192;          // 96 rows (n,t3) x 64, row-major

  // ---- phase 1: sp = relu(A[96x64] @ W2[64x64] + b2) -> spL[n][t3*64+c]
  {
    int ty = tid >> 4, tx = tid & 15;            // rows 6ty+i, cols 4tx+j
    float acc[6][4] = {{0.f}};
    for (int k0 = 0; k0 < 64; k0 += 32) {
      #pragma unroll
      for (int rep = 0; rep < 3; rep++) {        // As: 768 float4
        int idx = rep * 256 + tid;
        int m = idx >> 3, q4 = (idx & 7) * 4;
        *(float4*)&As[m * 36 + q4] = *(const float4*)(A + m * 64 + k0 + q4);
      }
      #pragma unroll
      for (int rep = 0; rep < 2; rep++) {        // Ws: [32][64] chunk of W2
        int idx = rep * 256 + tid;
        int kk = idx >> 4, c4 = (idx & 15) * 4;
        *(float4*)&Ws[kk * 64 + c4] = *(const float4*)(W2 + (size_t)(k0 + kk) * 64 + c4);
      }
      __syncthreads();
      #pragma unroll
      for (int k = 0; k < 32; k += 4) {
        float4 a[6], w[4];
        #pragma unroll
        for (int i = 0; i < 6; i++) a[i] = *(const float4*)&As[(6 * ty + i) * 36 + k];
        #pragma unroll
        for (int kk = 0; kk < 4; kk++) w[kk] = *(const float4*)&Ws[(k + kk) * 64 + 4 * tx];
        #pragma unroll
        for (int i = 0; i < 6; i++) {
          float av[4] = {a[i].x, a[i].y, a[i].z, a[i].w};
          #pragma unroll
          for (int kk = 0; kk < 4; kk++) {
            acc[i][0] += av[kk] * w[kk].x;
            acc[i][1] += av[kk] * w[kk].y;
            acc[i][2] += av[kk] * w[kk].z;
            acc[i][3] += av[kk] * w[kk].w;
          }
        }
      }
      __syncthreads();
    }
    float4 bv = *(const float4*)(b2 + 4 * tx);
    #pragma unroll
    for (int i = 0; i < 6; i++) {
      int m = 6 * ty + i;
      int n = m / 3, t3 = m % 3;
      float4 o;
      o.x = fmaxf(acc[i][0] + bv.x, 0.0f);
      o.y = fmaxf(acc[i][1] + bv.y, 0.0f);
      o.z = fmaxf(acc[i][2] + bv.z, 0.0f);
      o.w = fmaxf(acc[i][3] + bv.w, 0.0f);
      *(float4*)&spL[n * 196 + t3 * 64 + 4 * tx] = o;
    }
  }
  __syncthreads();

  // ---- phase 2: t1 = relu(spL[32x192] @ p1c[192x128] + pb1) -> t1L[32][132]
  {
    int ty = tid >> 5, tx = tid & 31;            // rows 4ty+i, cols 4tx+j
    float acc[4][4] = {{0.f}};
    for (int c12 = 0; c12 < 12; c12++) {
      #pragma unroll
      for (int rep = 0; rep < 2; rep++) {        // Ws: [16][128] chunk of p1c
        int idx = rep * 256 + tid;
        int kk = idx >> 5, c4 = (idx & 31) * 4;
        *(float4*)&Ws[kk * 128 + c4] = *(const float4*)(p1c + (size_t)(c12 * 16 + kk) * 128 + c4);
      }
      __syncthreads();
      int kbase = c12 * 16;
      #pragma unroll
      for (int k = 0; k < 16; k += 4) {
        float4 a[4], w[4];
        #pragma unroll
        for (int i = 0; i < 4; i++) a[i] = *(const float4*)&spL[(4 * ty + i) * 196 + kbase + k];
        #pragma unroll
        for (int kk = 0; kk < 4; kk++) w[kk] = *(const float4*)&Ws[(k + kk) * 128 + 4 * tx];
        #pragma unroll
        for (int i = 0; i < 4; i++) {
          float av[4] = {a[i].x, a[i].y, a[i].z, a[i].w};
          #pragma unroll
          for (int kk = 0; kk < 4; kk++) {
            acc[i][0] += av[kk] * w[kk].x;
            acc[i][1] += av[kk] * w[kk].y;
            acc[i][2] += av[kk] * w[kk].z;
            acc[i][3] += av[kk] * w[kk].w;
          }
        }
      }
      __syncthreads();
    }
    float4 bv = *(const float4*)(pb1 + 4 * tx);
    #pragma unroll
    for (int i = 0; i < 4; i++) {
      float4 o;
      o.x = fmaxf(acc[i][0] + bv.x, 0.0f);
      o.y = fmaxf(acc[i][1] + bv.y, 0.0f);
      o.z = fmaxf(acc[i][2] + bv.z, 0.0f);
      o.w = fmaxf(acc[i][3] + bv.w, 0.0f);
      *(float4*)&t1L[(4 * ty + i) * 132 + 4 * tx] = o;
    }
  }
  __syncthreads();

  // ---- phase 3: last = relu(t1L[32x128] @ p2c[128x64] + tc2b); out = last . ow + ob
  {
    int ty = tid >> 4, tx = tid & 15;            // rows 2ty+i, cols 4tx+j
    float acc[2][4] = {{0.f}};
    for (int c8 = 0; c8 < 8; c8++) {
      {                                          // Ws: [16][64] chunk of p2c
        int kk = tid >> 4, c4 = (tid & 15) * 4;
        *(float4*)&Ws[kk * 64 + c4] = *(const float4*)(p2c + (size_t)(c8 * 16 + kk) * 64 + c4);
      }
      __syncthreads();
      int kbase = c8 * 16;
      #pragma unroll
      for (int k = 0; k < 16; k += 4) {
        float4 a[2], w[4];
        #pragma unroll
        for (int i = 0; i < 2; i++) a[i] = *(const float4*)&t1L[(2 * ty + i) * 132 + kbase + k];
        #pragma unroll
        for (int kk = 0; kk < 4; kk++) w[kk] = *(const float4*)&Ws[(k + kk) * 64 + 4 * tx];
        #pragma unroll
        for (int i = 0; i < 2; i++) {
          float av[4] = {a[i].x, a[i].y, a[i].z, a[i].w};
          #pragma unroll
          for (int kk = 0; kk < 4; kk++) {
            acc[i][0] += av[kk] * w[kk].x;
            acc[i][1] += av[kk] * w[kk].y;
            acc[i][2] += av[kk] * w[kk].z;
            acc[i][3] += av[kk] * w[kk].w;
          }
        }
      }
      __syncthreads();
    }
    float4 bv = *(const float4*)(tc2b + 4 * tx);
    float4 o4 = *(const float4*)(ow + 4 * tx);
    float obv = obp[0];
    #pragma unroll
    for (int i = 0; i < 2; i++) {
      float v = fmaxf(acc[i][0] + bv.x, 0.0f) * o4.x
              + fmaxf(acc[i][1] + bv.y, 0.0f) * o4.y
              + fmaxf(acc[i][2] + bv.z, 0.0f) * o4.z
              + fmaxf(acc[i][3] + bv.w, 0.0f) * o4.w;
      v += __shfl_xor(v, 1, 64);
      v += __shfl_xor(v, 2, 64);
      v += __shfl_xor(v, 4, 64);
      v += __shfl_xor(v, 8, 64);
      if (tx == 0) out[nodeBase + 2 * ty + i] = v + obv;
    }
  }
}

// ---------------- launch ----------------

extern "C" void kernel_launch(void* const* d_in, const int* in_sizes, int n_in,
                              void* d_out, int out_size, void* d_ws, size_t ws_size,
                              hipStream_t stream) {
  const float* X    = (const float*)d_in[0];
  const int*   EI   = (const int*)  d_in[1];
  const float* EW   = (const float*)d_in[2];
  const float* W1   = (const float*)d_in[3];
  const float* B1   = (const float*)d_in[4];
  const float* W2   = (const float*)d_in[5];
  const float* B2   = (const float*)d_in[6];
  const float* TC1W = (const float*)d_in[7];
  const float* TC1B = (const float*)d_in[8];
  const float* TC2W = (const float*)d_in[9];
  const float* TC2B = (const float*)d_in[10];
  const float* OW   = (const float*)d_in[11];
  const float* OB   = (const float*)d_in[12];
  float* out = (float*)d_out;

  char* base = (char*)d_ws;
  size_t off = 0;
  auto alloc = [&](size_t bytes) -> char* {
    char* p = base + off;
    off += (bytes + 255) & ~(size_t)255;
    return p;
  };
  float* dinv  = (float*)alloc(N_NODES * 4);
  int*   cur   = (int*)  alloc(N_NODES * 4);
  int*   mcnt  = (int*)  alloc(N_NODES * 4);
  int*   csrc  = (int*)  alloc((size_t)N_NODES * CAP * 4);
  float* cnorm = (float*)alloc((size_t)N_NODES * CAP * 4);
  float* p1c   = (float*)alloc(192 * 128 * 4);
  float* p2c   = (float*)alloc(128 * 64 * 4);
  float* pb1   = (float*)alloc(128 * 4);
  const size_t BIG = (size_t)80000 * 192;
  ushort* h1 = (ushort*)alloc(BIG * 2);    // fp16 h1: 30.7 MB, 3.84 MB/batch slab
  float*  ah = (float*) alloc(BIG * 4);

  hipMemsetAsync(cur, 0, N_NODES * 4, stream);
  k_fillfix<<<625, 256, 0, stream>>>(EI, EW, cur, csrc, cnorm);
  k_degpad<<<2500, 256, 0, stream>>>(cur, csrc, cnorm, dinv, mcnt);
  // wnorm (blocks 0..2499) + weight pack (blocks 2500..2628) in one dispatch
  k_wnormpack<<<2629, 256, 0, stream>>>(cur, csrc, dinv, cnorm, TC1W, TC2W, TC1B, p1c, p2c, pb1);

  // layer 1 (agg + W1 + relu), t=9..11 fused; h1 fp16 packed (t0,t1 half2 | t2)
  k_aggg1<<<20000, 256, 0, stream>>>(X, dinv, mcnt, csrc, cnorm, W1, B1, h1);
  // layer 2 aggregation: fp16 L2-resident gather, round-0 proven structure
  k_agg3m16<<<20000, 256, 0, stream>>>(h1, dinv, mcnt, csrc, cnorm, ah);
  // fused W2-GEMM + conv1 + conv2 + out (32 nodes/block, LDS-staged weights) -- FROZEN
  k_fused<<<2500, 256, 0, stream>>>(ah, W2, B2, p1c, pb1, p2c, TC2B, OW, OB, out);
}

// Round 6
// 200.436 us; speedup vs baseline: 4.4784x; 1.4379x over previous
//
#include <hip/hip_runtime.h>
#include <hip/hip_fp16.h>

#define N_NODES 10000
#define EDGES   160000
#define BATCH   8
#define TT      12
#define HID     64
#define CAP     64       // fixed edge-slot capacity per node (avg deg 16, P(deg>64) ~ 0)

typedef _Float16 f16x8 __attribute__((ext_vector_type(8)));
typedef _Float16 f16x4 __attribute__((ext_vector_type(4)));
typedef float    f32x4 __attribute__((ext_vector_type(4)));

// permutation of k within a 32-k group so one b128 (8 halves) = one MFMA fragment:
// fragment wants k = {4g..4g+3, 16+4g..16+4g+3} at lane group g -> store k at
// pos = 8*g + 4*h + j  (g=(k>>2)&3, h=k>>4, j=k&3)
__host__ __device__ __forceinline__ int kperm(int k31) {
  return (((k31 >> 2) & 3) << 3) + ((k31 >> 4) << 2) + (k31 & 3);
}

// ---------------- CSR build (fixed-capacity, no scan) ----------------

__global__ __launch_bounds__(256) void k_fillfix(const int* __restrict__ ei,
                                                 const float* __restrict__ ew,
                                                 int* __restrict__ cur,
                                                 int* __restrict__ csrc,
                                                 float* __restrict__ cnorm) {
  int g = blockIdx.x * 256 + threadIdx.x;
  if (g < EDGES) {
    int s = ei[g], d = ei[EDGES + g];
    int slot = atomicAdd(&cur[d], 1);
    csrc[d * CAP + slot]  = s;
    cnorm[d * CAP + slot] = ew[g];
  }
}

__global__ __launch_bounds__(256) void k_degpad(const int* __restrict__ cur,
                                                int* __restrict__ csrc,
                                                float* __restrict__ cnorm,
                                                float* __restrict__ dinv,
                                                int* __restrict__ mcnt) {
  int n = blockIdx.x * 4 + (threadIdx.x >> 6);
  int lane = threadIdx.x & 63;
  int cnt = cur[n];
  int m = (cnt + 7) & ~7;
  int base = n * CAP;
  if (lane >= cnt && lane < m) { csrc[base + lane] = 0; cnorm[base + lane] = 0.0f; }
  float s = (lane < cnt) ? cnorm[base + lane] : 0.0f;
  #pragma unroll
  for (int off = 32; off > 0; off >>= 1) s += __shfl_xor(s, off, 64);
  if (lane == 0) {
    dinv[n] = 1.0f / sqrtf(s + 1.0f);
    mcnt[n] = m;
  }
}

// merged: blocks 0..2499 = wnorm; blocks 2500.. = weight pack into fp16,
// TRANSPOSED [col][k] with per-32-group kperm (MFMA B-fragment = one b128):
//  p1ct ushort[128][192], p2ct ushort[64][128], W2t ushort[64][64], pb1 float[128]
__global__ __launch_bounds__(256) void k_wnormpack(const int* __restrict__ cur,
                                                   const int* __restrict__ csrc,
                                                   const float* __restrict__ dinv,
                                                   float* __restrict__ cnorm,
                                                   const float* __restrict__ tc1w,
                                                   const float* __restrict__ tc2w,
                                                   const float* __restrict__ tc1b,
                                                   const float* __restrict__ W2,
                                                   ushort* __restrict__ p1ct,
                                                   ushort* __restrict__ p2ct,
                                                   ushort* __restrict__ W2t,
                                                   float* __restrict__ pb1) {
  if (blockIdx.x < 2500) {
    int n = blockIdx.x * 4 + (threadIdx.x >> 6);
    int lane = threadIdx.x & 63;
    int cnt = cur[n];
    int m = (cnt + 7) & ~7;
    if (lane < m) {
      int idx = n * CAP + lane;
      cnorm[idx] = cnorm[idx] * dinv[csrc[idx]] * dinv[n];
    }
  } else {
    int g = (blockIdx.x - 2500) * 256 + threadIdx.x;
    if (g < 24576) {                       // p1ct: k = t3*64+i, col = t'*64+o
      int kk = g >> 7, col = g & 127;
      int t3 = kk >> 6, i = kk & 63;
      int half = col >> 6, o = col & 63;
      float v;
      if (half == 0) v = tc1w[o * 192 + i * 3 + t3];
      else           v = (t3 == 0) ? 0.0f : tc1w[o * 192 + i * 3 + (t3 - 1)];
      p1ct[col * 192 + (kk >> 5) * 32 + kperm(kk & 31)] = __half_as_ushort(__float2half_rn(v));
    } else if (g < 32768) {                // p2ct: k = t'*64+i, col = o
      int r = g - 24576;
      int kk = r >> 6, o = r & 63;
      int gk = kk >> 6, i = kk & 63;
      float v = tc2w[o * 192 + i * 3 + gk];
      p2ct[o * 128 + (kk >> 5) * 32 + kperm(kk & 31)] = __half_as_ushort(__float2half_rn(v));
    } else if (g < 36864) {                // W2t: k = c_in, col = c_out
      int r = g - 32768;
      int kk = r >> 6, c = r & 63;
      float v = W2[kk * 64 + c];
      W2t[c * 64 + (kk >> 5) * 32 + kperm(kk & 31)] = __half_as_ushort(__float2half_rn(v));
    } else if (g < 36992) {
      int r = g - 36864;
      pb1[r] = tc1b[r & 63];
    }
  }
}

// ---------------- GCN layer 1: fused agg(X) @ W1 + b1, relu ----------------
// h1 FP16 (3.84MB/batch slab -> L2-resident gather). Layout (ushort units):
// [0..128) = interleaved (t0[c],t1[c]) half2 at 2c; [128..192) = t2[c].

__global__ __launch_bounds__(256) void k_aggg1(const float* __restrict__ X,
                                               const float* __restrict__ dinv,
                                               const int* __restrict__ mcnt,
                                               const int* __restrict__ csrc,
                                               const float* __restrict__ cnorm,
                                               const float* __restrict__ W1,
                                               const float* __restrict__ b1,
                                               ushort* __restrict__ h1) {
  int b = blockIdx.x & 7;                    // batch -> XCD affinity
  int grp = blockIdx.x >> 3;                 // 0..2499
  int n = grp * 4 + (threadIdx.x >> 6);
  int lane = threadIdx.x & 63;
  const float2* x0 = (const float2*)(X + (size_t)(b * TT + 9)  * N_NODES * 2);
  const float2* x1 = (const float2*)(X + (size_t)(b * TT + 10) * N_NODES * 2);
  const float2* x2 = (const float2*)(X + (size_t)(b * TT + 11) * N_NODES * 2);
  float a0x = 0.f, a0y = 0.f, a1x = 0.f, a1y = 0.f, a2x = 0.f, a2y = 0.f;
  int m = mcnt[n];
  if (lane < m) {
    int idx = n * CAP + lane;
    float w = cnorm[idx];
    int s = csrc[idx];
    float2 s0 = x0[s], s1 = x1[s], s2v = x2[s];
    a0x = w * s0.x;  a0y = w * s0.y;
    a1x = w * s1.x;  a1y = w * s1.y;
    a2x = w * s2v.x; a2y = w * s2v.y;
  }
  if (lane == 0) {  // self-loop term
    float di = dinv[n];
    float sd = di * di;
    float2 v0 = x0[n], v1 = x1[n], v2 = x2[n];
    a0x += sd * v0.x; a0y += sd * v0.y;
    a1x += sd * v1.x; a1y += sd * v1.y;
    a2x += sd * v2.x; a2y += sd * v2.y;
  }
  #pragma unroll
  for (int off = 32; off > 0; off >>= 1) {
    a0x += __shfl_xor(a0x, off, 64);
    a0y += __shfl_xor(a0y, off, 64);
    a1x += __shfl_xor(a1x, off, 64);
    a1y += __shfl_xor(a1y, off, 64);
    a2x += __shfl_xor(a2x, off, 64);
    a2y += __shfl_xor(a2y, off, 64);
  }
  int c = lane;
  float w0 = W1[c], w1 = W1[64 + c], bc = b1[c];
  float r0 = fmaxf(a0x * w0 + a0y * w1 + bc, 0.0f);
  float r1 = fmaxf(a1x * w0 + a1y * w1 + bc, 0.0f);
  float r2 = fmaxf(a2x * w0 + a2y * w1 + bc, 0.0f);
  ushort* row = h1 + ((size_t)(b * N_NODES + n)) * 192;
  *(__half2*)(row + 2 * c)  = __floats2half2_rn(r0, r1);
  *(__half*)(row + 128 + c) = __float2half_rn(r2);
}

// ---------------- GCN layer 2 aggregation: fp16 L2-resident gather (proven) ----------------
__global__ __launch_bounds__(256) void k_agg3m16(const ushort* __restrict__ h1,
                                                 const float* __restrict__ dinv,
                                                 const int* __restrict__ mcnt,
                                                 const int* __restrict__ csrc,
                                                 const float* __restrict__ cnorm,
                                                 float* __restrict__ ah) {
  int b = blockIdx.x & 7;                    // batch -> XCD affinity
  int grp = blockIdx.x >> 3;                 // 0..2499
  int n = grp * 4 + (threadIdx.x >> 6);
  int c = threadIdx.x & 63;
  const ushort* hb = h1 + (size_t)b * N_NODES * 192;
  float acc0 = 0.f, acc1 = 0.f, acc2 = 0.f;
  int m = mcnt[n];                           // <= 64, multiple of 8
  int idx = n * CAP + c;
  int ic = (c < m) ? idx : n * CAP;
  int sv = csrc[ic] * 192;                   // ushort offset of source row
  float wf = (c < m) ? cnorm[idx] : 0.0f;
  int wb = __float_as_int(wf);
  for (int e = 0; e < m; e += 8) {
    #pragma unroll
    for (int u = 0; u < 8; u++) {
      int   off = __builtin_amdgcn_readlane(sv, e + u);
      float w   = __int_as_float(__builtin_amdgcn_readlane(wb, e + u));
      const ushort* p = hb + off;
      float2 f01 = __half22float2(*(const __half2*)(p + 2 * c));
      float  t2v = __half2float(*(const __half*)(p + 128 + c));
      acc0 += w * f01.x;
      acc1 += w * f01.y;
      acc2 += w * t2v;
    }
  }
  float di = dinv[n];
  float s2 = di * di;
  const ushort* sr = hb + (size_t)n * 192;
  float2 fs = __half22float2(*(const __half2*)(sr + 2 * c));
  float  fst = __half2float(*(const __half*)(sr + 128 + c));
  size_t ob = ((size_t)(b * N_NODES + n)) * 192 + c;
  ah[ob]       = acc0 + s2 * fs.x;
  ah[ob + 64]  = acc1 + s2 * fs.y;
  ah[ob + 128] = acc2 + s2 * fst;
}

// ---------------- fused epilogue v5: fp16 MFMA (fp32 accumulate) ----------------
// v2 was DS-pipe-bound (~736 ds_read_b128/wave ~ 143us model ~ 133us measured).
// v5: all three GEMMs on mfma_f32_16x16x32_f16; every LDS tile is fp16, k-permuted
// (kperm: one b128 = one fragment) and XOR-swizzled (oh ^= (row&7)<<3 in halves) for
// bank balance. DS/wave ~120, FMAs on matrix pipe. LDS 41,472B -> 3 blocks/CU.
// Wave w owns a 16-col strip (phase1/3) or 32-col strip (phase2); fragment maps:
//   A: row = lane&15, k-group g = lane>>4;  B: col = lane&15;  D: col = lane&15,
//   row = 4*(lane>>4) + reg  (m89-verified, dtype-independent).
__global__ __launch_bounds__(256, 3) void k_fused(const float* __restrict__ ah,
                                                  const ushort* __restrict__ W2t,
                                                  const float* __restrict__ b2,
                                                  const ushort* __restrict__ p1ct,
                                                  const float* __restrict__ pb1,
                                                  const ushort* __restrict__ p2ct,
                                                  const float* __restrict__ tc2b,
                                                  const float* __restrict__ ow,
                                                  const float* __restrict__ obp,
                                                  float* __restrict__ out) {
  __shared__ __align__(16) ushort smem[20736];     // 41,472 B
  ushort* spL = smem;                              // [32][192]
  ushort* As  = smem + 6144;                       // [96][64]   (phase 1)
  ushort* W2s = smem + 12288;                      // [64][64]   (phase 1)
  ushort* Wc  = smem + 6144;                       // [128][64] chunk / [64][128] p2c
  ushort* t1L = smem + 16384;                      // [32][128]
  float*  red = (float*)(smem + 20480);            // [4][32]

  int tid = threadIdx.x;
  int lane = tid & 63, w = tid >> 6;
  int l15 = lane & 15, g = lane >> 4;
  size_t nodeBase = (size_t)blockIdx.x * 32;       // in (b*N+n) units
  const float* A = ah + nodeBase * 192;            // 96 rows x 64, row-major fp32

  // ---- stage As: fp32 -> fp16, quad-permuted + swizzled. quad q of 32-group:
  // pq = ((q&3)<<1)|(q>>2) keeps 4 consecutive k per 8B packet.
  #pragma unroll
  for (int rep = 0; rep < 6; rep++) {
    int idx = rep * 256 + tid;                     // 1536 float4 quads
    int m = idx >> 4, q = idx & 15;
    float4 v = *(const float4*)(A + m * 64 + q * 4);
    int s = q >> 3, qq = q & 7;
    int pq = ((qq & 3) << 1) | (qq >> 2);
    int oh = s * 32 + pq * 4;
    f16x4 hv = { (_Float16)v.x, (_Float16)v.y, (_Float16)v.z, (_Float16)v.w };
    *(f16x4*)&As[m * 64 + (oh ^ ((m & 7) << 3))] = hv;
  }
  // ---- stage W2s (already fp16+permuted in global; add swizzle)
  #pragma unroll
  for (int r = 0; r < 2; r++) {
    int u = r * 256 + tid;                         // 512 x 8 halves
    int cl = u >> 3, hu = u & 7;
    *(uint4*)&W2s[cl * 64 + ((hu * 8) ^ ((cl & 7) << 3))] =
        *(const uint4*)&W2t[cl * 64 + hu * 8];
  }
  __syncthreads();

  // ---- phase 1: sp = relu(As[96x64] @ W2[64x64] + b2); wave w = cols 16w..16w+15
  {
    int col = w * 16 + l15;
    float bias = b2[col];
    f32x4 acc[6];
    #pragma unroll
    for (int i = 0; i < 6; i++) acc[i] = (f32x4){0.f, 0.f, 0.f, 0.f};
    #pragma unroll
    for (int s = 0; s < 2; s++) {
      int oh = s * 32 + 8 * g;
      f16x8 bf = *(const f16x8*)&W2s[col * 64 + (oh ^ ((col & 7) << 3))];
      #pragma unroll
      for (int mi = 0; mi < 6; mi++) {
        int row = mi * 16 + l15;
        f16x8 af = *(const f16x8*)&As[row * 64 + (oh ^ ((row & 7) << 3))];
        acc[mi] = __builtin_amdgcn_mfma_f32_16x16x32_f16(af, bf, acc[mi], 0, 0, 0);
      }
    }
    // epilogue: D row m=(3n+t3) col c -> spL A-layout row n, k = t3*64+c (perm+swz)
    #pragma unroll
    for (int mi = 0; mi < 6; mi++) {
      #pragma unroll
      for (int r = 0; r < 4; r++) {
        int m = mi * 16 + 4 * g + r;
        int n = m / 3, t3 = m - 3 * n;
        float v = fmaxf(acc[mi][r] + bias, 0.0f);
        int k = t3 * 64 + col;
        int oh = (k >> 5) * 32 + kperm(k & 31);
        *(_Float16*)&spL[n * 192 + (oh ^ ((n & 7) << 3))] = (_Float16)v;
      }
    }
  }
  __syncthreads();                                 // As/W2s dead; spL ready

  // ---- phase 2: t1 = relu(spL[32x192] @ p1c[192x128] + pb1); 3 K-chunks of 64
  f32x4 acc2[2][2];
  #pragma unroll
  for (int i = 0; i < 2; i++)
    #pragma unroll
    for (int j = 0; j < 2; j++) acc2[i][j] = (f32x4){0.f, 0.f, 0.f, 0.f};
  int c0 = 32 * w + l15, c1 = c0 + 16;             // wave w cols {32w..+15, 32w+16..+31}
  for (int cc = 0; cc < 3; cc++) {
    #pragma unroll
    for (int r = 0; r < 4; r++) {                  // stage [128 col][64 k] chunk
      int u = r * 256 + tid;
      int cl = u >> 3, hu = u & 7;
      *(uint4*)&Wc[cl * 64 + ((hu * 8) ^ ((cl & 7) << 3))] =
          *(const uint4*)&p1ct[cl * 192 + cc * 64 + hu * 8];
    }
    __syncthreads();
    #pragma unroll
    for (int ks = 0; ks < 2; ks++) {
      int ohB = ks * 32 + 8 * g;
      f16x8 bf0 = *(const f16x8*)&Wc[c0 * 64 + (ohB ^ ((c0 & 7) << 3))];
      f16x8 bf1 = *(const f16x8*)&Wc[c1 * 64 + (ohB ^ ((c1 & 7) << 3))];
      int ohA = (cc * 2 + ks) * 32 + 8 * g;
      #pragma unroll
      for (int mi = 0; mi < 2; mi++) {
        int row = mi * 16 + l15;
        f16x8 af = *(const f16x8*)&spL[row * 192 + (ohA ^ ((row & 7) << 3))];
        acc2[mi][0] = __builtin_amdgcn_mfma_f32_16x16x32_f16(af, bf0, acc2[mi][0], 0, 0, 0);
        acc2[mi][1] = __builtin_amdgcn_mfma_f32_16x16x32_f16(af, bf1, acc2[mi][1], 0, 0, 0);
      }
    }
    __syncthreads();
  }
  // epilogue: t1L A-layout row n, k = col (perm+swz)
  {
    float bz0 = pb1[c0], bz1 = pb1[c1];
    int oh0 = (c0 >> 5) * 32 + kperm(c0 & 31);
    int oh1 = (c1 >> 5) * 32 + kperm(c1 & 31);
    #pragma unroll
    for (int mi = 0; mi < 2; mi++) {
      #pragma unroll
      for (int r = 0; r < 4; r++) {
        int n = mi * 16 + 4 * g + r;
        float v0 = fmaxf(acc2[mi][0][r] + bz0, 0.0f);
        float v1 = fmaxf(acc2[mi][1][r] + bz1, 0.0f);
        *(_Float16*)&t1L[n * 128 + (oh0 ^ ((n & 7) << 3))] = (_Float16)v0;
        *(_Float16*)&t1L[n * 128 + (oh1 ^ ((n & 7) << 3))] = (_Float16)v1;
      }
    }
  }
  // ---- stage p2cs [64 col][128 k] into Wc (t1L and Wc disjoint; one barrier)
  #pragma unroll
  for (int r = 0; r < 4; r++) {
    int u = r * 256 + tid;                         // 1024 x 8 halves
    int cl = u >> 4, hu = u & 15;
    *(uint4*)&Wc[cl * 128 + ((hu * 8) ^ ((cl & 7) << 3))] =
        *(const uint4*)&p2ct[cl * 128 + hu * 8];
  }
  __syncthreads();

  // ---- phase 3: last = relu(t1L[32x128] @ p2c[128x64] + tc2b); dot with ow
  {
    int col = 16 * w + l15;
    f32x4 acc3[2];
    acc3[0] = (f32x4){0.f, 0.f, 0.f, 0.f};
    acc3[1] = (f32x4){0.f, 0.f, 0.f, 0.f};
    #pragma unroll
    for (int s = 0; s < 4; s++) {
      int oh = s * 32 + 8 * g;
      f16x8 bf = *(const f16x8*)&Wc[col * 128 + (oh ^ ((col & 7) << 3))];
      #pragma unroll
      for (int mi = 0; mi < 2; mi++) {
        int row = mi * 16 + l15;
        f16x8 af = *(const f16x8*)&t1L[row * 128 + (oh ^ ((row & 7) << 3))];
        acc3[mi] = __builtin_amdgcn_mfma_f32_16x16x32_f16(af, bf, acc3[mi], 0, 0, 0);
      }
    }
    float tb = tc2b[col], o4 = ow[col];
    float s4[2][4];
    #pragma unroll
    for (int mi = 0; mi < 2; mi++)
      #pragma unroll
      for (int r = 0; r < 4; r++)
        s4[mi][r] = fmaxf(acc3[mi][r] + tb, 0.0f) * o4;
    #pragma unroll
    for (int off = 1; off <= 8; off <<= 1) {
      #pragma unroll
      for (int mi = 0; mi < 2; mi++)
        #pragma unroll
        for (int r = 0; r < 4; r++)
          s4[mi][r] += __shfl_xor(s4[mi][r], off, 64);
    }
    if (l15 == 0) {
      #pragma unroll
      for (int mi = 0; mi < 2; mi++) {
        float4 o;
        o.x = s4[mi][0]; o.y = s4[mi][1]; o.z = s4[mi][2]; o.w = s4[mi][3];
        *(float4*)&red[w * 32 + mi * 16 + 4 * g] = o;
      }
    }
  }
  __syncthreads();
  if (tid < 32) {
    float v = red[tid] + red[32 + tid] + red[64 + tid] + red[96 + tid] + obp[0];
    out[nodeBase + tid] = v;
  }
}

// ---------------- launch ----------------

extern "C" void kernel_launch(void* const* d_in, const int* in_sizes, int n_in,
                              void* d_out, int out_size, void* d_ws, size_t ws_size,
                              hipStream_t stream) {
  const float* X    = (const float*)d_in[0];
  const int*   EI   = (const int*)  d_in[1];
  const float* EW   = (const float*)d_in[2];
  const float* W1   = (const float*)d_in[3];
  const float* B1   = (const float*)d_in[4];
  const float* W2   = (const float*)d_in[5];
  const float* B2   = (const float*)d_in[6];
  const float* TC1W = (const float*)d_in[7];
  const float* TC1B = (const float*)d_in[8];
  const float* TC2W = (const float*)d_in[9];
  const float* TC2B = (const float*)d_in[10];
  const float* OW   = (const float*)d_in[11];
  const float* OB   = (const float*)d_in[12];
  float* out = (float*)d_out;

  char* base = (char*)d_ws;
  size_t off = 0;
  auto alloc = [&](size_t bytes) -> char* {
    char* p = base + off;
    off += (bytes + 255) & ~(size_t)255;
    return p;
  };
  float*  dinv  = (float*) alloc(N_NODES * 4);
  int*    cur   = (int*)   alloc(N_NODES * 4);
  int*    mcnt  = (int*)   alloc(N_NODES * 4);
  int*    csrc  = (int*)   alloc((size_t)N_NODES * CAP * 4);
  float*  cnorm = (float*) alloc((size_t)N_NODES * CAP * 4);
  ushort* p1ct  = (ushort*)alloc(128 * 192 * 2);
  ushort* p2ct  = (ushort*)alloc(64 * 128 * 2);
  ushort* W2t   = (ushort*)alloc(64 * 64 * 2);
  float*  pb1   = (float*) alloc(128 * 4);
  const size_t BIG = (size_t)80000 * 192;
  ushort* h1 = (ushort*)alloc(BIG * 2);    // fp16 h1: 3.84 MB/batch slab (L2-resident)
  float*  ah = (float*) alloc(BIG * 4);

  hipMemsetAsync(cur, 0, N_NODES * 4, stream);
  k_fillfix<<<625, 256, 0, stream>>>(EI, EW, cur, csrc, cnorm);
  k_degpad<<<2500, 256, 0, stream>>>(cur, csrc, cnorm, dinv, mcnt);
  // wnorm (blocks 0..2499) + fp16 transposed/permuted weight pack (blocks 2500..2644)
  k_wnormpack<<<2645, 256, 0, stream>>>(cur, csrc, dinv, cnorm, TC1W, TC2W, TC1B, W2,
                                        p1ct, p2ct, W2t, pb1);

  // layer 1 (agg + W1 + relu), t=9..11 fused; h1 fp16 packed (t0,t1 half2 | t2)
  k_aggg1<<<20000, 256, 0, stream>>>(X, dinv, mcnt, csrc, cnorm, W1, B1, h1);
  // layer 2 aggregation: fp16 L2-resident gather (round-5 proven, 288us config)
  k_agg3m16<<<20000, 256, 0, stream>>>(h1, dinv, mcnt, csrc, cnorm, ah);
  // fused W2-GEMM + conv1 + conv2 + out: v5 fp16 MFMA epilogue
  k_fused<<<2500, 256, 0, stream>>>(ah, W2t, B2, p1ct, pb1, p2ct, TC2B, OW, OB, out);
}

// Round 7
// 194.735 us; speedup vs baseline: 4.6095x; 1.0293x over previous
//
#include <hip/hip_runtime.h>
#include <hip/hip_fp16.h>

#define N_NODES 10000
#define EDGES   160000
#define BATCH   8
#define TT      12
#define HID     64
#define CAP     64       // fixed edge-slot capacity per node (avg deg 16, P(deg>64) ~ 0)

typedef _Float16 f16x8 __attribute__((ext_vector_type(8)));
typedef _Float16 f16x4 __attribute__((ext_vector_type(4)));
typedef float    f32x4 __attribute__((ext_vector_type(4)));

// permutation of k within a 32-k group so one b128 (8 halves) = one MFMA fragment:
// fragment wants k = {4g..4g+3, 16+4g..16+4g+3} at lane group g -> store k at
// pos = 8*g + 4*h + j  (g=(k>>2)&3, h=k>>4, j=k&3).  HW-verified (round 6 passed).
__host__ __device__ __forceinline__ int kperm(int k31) {
  return (((k31 >> 2) & 3) << 3) + ((k31 >> 4) << 2) + (k31 & 3);
}

// ---------------- CSR build (fixed-capacity, no scan) ----------------

__global__ __launch_bounds__(256) void k_fillfix(const int* __restrict__ ei,
                                                 const float* __restrict__ ew,
                                                 int* __restrict__ cur,
                                                 int* __restrict__ csrc,
                                                 float* __restrict__ cnorm) {
  int g = blockIdx.x * 256 + threadIdx.x;
  if (g < EDGES) {
    int s = ei[g], d = ei[EDGES + g];
    int slot = atomicAdd(&cur[d], 1);
    csrc[d * CAP + slot]  = s;
    cnorm[d * CAP + slot] = ew[g];
  }
}

__global__ __launch_bounds__(256) void k_degpad(const int* __restrict__ cur,
                                                int* __restrict__ csrc,
                                                float* __restrict__ cnorm,
                                                float* __restrict__ dinv,
                                                int* __restrict__ mcnt) {
  int n = blockIdx.x * 4 + (threadIdx.x >> 6);
  int lane = threadIdx.x & 63;
  int cnt = cur[n];
  int m = (cnt + 7) & ~7;
  int base = n * CAP;
  if (lane >= cnt && lane < m) { csrc[base + lane] = 0; cnorm[base + lane] = 0.0f; }
  float s = (lane < cnt) ? cnorm[base + lane] : 0.0f;
  #pragma unroll
  for (int off = 32; off > 0; off >>= 1) s += __shfl_xor(s, off, 64);
  if (lane == 0) {
    dinv[n] = 1.0f / sqrtf(s + 1.0f);
    mcnt[n] = m;
  }
}

// merged: blocks 0..2499 = wnorm; blocks 2500.. = weight pack into fp16,
// TRANSPOSED [col][k] with per-32-group kperm (MFMA B-fragment = one b128):
//  p1ct ushort[128][192], p2ct ushort[64][128], W2t ushort[64][64], pb1 float[128]
__global__ __launch_bounds__(256) void k_wnormpack(const int* __restrict__ cur,
                                                   const int* __restrict__ csrc,
                                                   const float* __restrict__ dinv,
                                                   float* __restrict__ cnorm,
                                                   const float* __restrict__ tc1w,
                                                   const float* __restrict__ tc2w,
                                                   const float* __restrict__ tc1b,
                                                   const float* __restrict__ W2,
                                                   ushort* __restrict__ p1ct,
                                                   ushort* __restrict__ p2ct,
                                                   ushort* __restrict__ W2t,
                                                   float* __restrict__ pb1) {
  if (blockIdx.x < 2500) {
    int n = blockIdx.x * 4 + (threadIdx.x >> 6);
    int lane = threadIdx.x & 63;
    int cnt = cur[n];
    int m = (cnt + 7) & ~7;
    if (lane < m) {
      int idx = n * CAP + lane;
      cnorm[idx] = cnorm[idx] * dinv[csrc[idx]] * dinv[n];
    }
  } else {
    int g = (blockIdx.x - 2500) * 256 + threadIdx.x;
    if (g < 24576) {                       // p1ct: k = t3*64+i, col = t'*64+o
      int kk = g >> 7, col = g & 127;
      int t3 = kk >> 6, i = kk & 63;
      int half = col >> 6, o = col & 63;
      float v;
      if (half == 0) v = tc1w[o * 192 + i * 3 + t3];
      else           v = (t3 == 0) ? 0.0f : tc1w[o * 192 + i * 3 + (t3 - 1)];
      p1ct[col * 192 + (kk >> 5) * 32 + kperm(kk & 31)] = __half_as_ushort(__float2half_rn(v));
    } else if (g < 32768) {                // p2ct: k = t'*64+i, col = o
      int r = g - 24576;
      int kk = r >> 6, o = r & 63;
      int gk = kk >> 6, i = kk & 63;
      float v = tc2w[o * 192 + i * 3 + gk];
      p2ct[o * 128 + (kk >> 5) * 32 + kperm(kk & 31)] = __half_as_ushort(__float2half_rn(v));
    } else if (g < 36864) {                // W2t: k = c_in, col = c_out
      int r = g - 32768;
      int kk = r >> 6, c = r & 63;
      float v = W2[kk * 64 + c];
      W2t[c * 64 + (kk >> 5) * 32 + kperm(kk & 31)] = __half_as_ushort(__float2half_rn(v));
    } else if (g < 36992) {
      int r = g - 36864;
      pb1[r] = tc1b[r & 63];
    }
  }
}

// ---------------- GCN layer 1: fused agg(X) @ W1 + b1, relu ----------------
// h1 FP16 (3.84MB/batch slab -> L2-resident gather). Layout (ushort units):
// [0..128) = interleaved (t0[c],t1[c]) half2 at 2c; [128..192) = t2[c].

__global__ __launch_bounds__(256) void k_aggg1(const float* __restrict__ X,
                                               const float* __restrict__ dinv,
                                               const int* __restrict__ mcnt,
                                               const int* __restrict__ csrc,
                                               const float* __restrict__ cnorm,
                                               const float* __restrict__ W1,
                                               const float* __restrict__ b1,
                                               ushort* __restrict__ h1) {
  int b = blockIdx.x & 7;                    // batch -> XCD affinity
  int grp = blockIdx.x >> 3;                 // 0..2499
  int n = grp * 4 + (threadIdx.x >> 6);
  int lane = threadIdx.x & 63;
  const float2* x0 = (const float2*)(X + (size_t)(b * TT + 9)  * N_NODES * 2);
  const float2* x1 = (const float2*)(X + (size_t)(b * TT + 10) * N_NODES * 2);
  const float2* x2 = (const float2*)(X + (size_t)(b * TT + 11) * N_NODES * 2);
  float a0x = 0.f, a0y = 0.f, a1x = 0.f, a1y = 0.f, a2x = 0.f, a2y = 0.f;
  int m = mcnt[n];
  if (lane < m) {
    int idx = n * CAP + lane;
    float w = cnorm[idx];
    int s = csrc[idx];
    float2 s0 = x0[s], s1 = x1[s], s2v = x2[s];
    a0x = w * s0.x;  a0y = w * s0.y;
    a1x = w * s1.x;  a1y = w * s1.y;
    a2x = w * s2v.x; a2y = w * s2v.y;
  }
  if (lane == 0) {  // self-loop term
    float di = dinv[n];
    float sd = di * di;
    float2 v0 = x0[n], v1 = x1[n], v2 = x2[n];
    a0x += sd * v0.x; a0y += sd * v0.y;
    a1x += sd * v1.x; a1y += sd * v1.y;
    a2x += sd * v2.x; a2y += sd * v2.y;
  }
  #pragma unroll
  for (int off = 32; off > 0; off >>= 1) {
    a0x += __shfl_xor(a0x, off, 64);
    a0y += __shfl_xor(a0y, off, 64);
    a1x += __shfl_xor(a1x, off, 64);
    a1y += __shfl_xor(a1y, off, 64);
    a2x += __shfl_xor(a2x, off, 64);
    a2y += __shfl_xor(a2y, off, 64);
  }
  int c = lane;
  float w0 = W1[c], w1 = W1[64 + c], bc = b1[c];
  float r0 = fmaxf(a0x * w0 + a0y * w1 + bc, 0.0f);
  float r1 = fmaxf(a1x * w0 + a1y * w1 + bc, 0.0f);
  float r2 = fmaxf(a2x * w0 + a2y * w1 + bc, 0.0f);
  ushort* row = h1 + ((size_t)(b * N_NODES + n)) * 192;
  *(__half2*)(row + 2 * c)  = __floats2half2_rn(r0, r1);
  *(__half*)(row + 128 + c) = __float2half_rn(r2);
}

// ---------------- GCN layer 2 aggregation: fp16 L2-resident gather ----------------
// NEW: ah is stored FP16 and ALREADY KPERM'D (As k-layout): row m=3n+t3, 64 halves,
// pos = (c>>5)*32 + kperm(c&31). Bitwise-identical to round 6 (same fp32 accum, same
// single round-to-fp16 — it just happens here instead of in k_fused staging), but
// halves ah write+read traffic (61MB -> 30.7MB each way).
__global__ __launch_bounds__(256) void k_agg3m16(const ushort* __restrict__ h1,
                                                 const float* __restrict__ dinv,
                                                 const int* __restrict__ mcnt,
                                                 const int* __restrict__ csrc,
                                                 const float* __restrict__ cnorm,
                                                 ushort* __restrict__ ah16) {
  int b = blockIdx.x & 7;                    // batch -> XCD affinity
  int grp = blockIdx.x >> 3;                 // 0..2499
  int n = grp * 4 + (threadIdx.x >> 6);
  int c = threadIdx.x & 63;
  const ushort* hb = h1 + (size_t)b * N_NODES * 192;
  float acc0 = 0.f, acc1 = 0.f, acc2 = 0.f;
  int m = mcnt[n];                           // <= 64, multiple of 8
  int idx = n * CAP + c;
  int ic = (c < m) ? idx : n * CAP;
  int sv = csrc[ic] * 192;                   // ushort offset of source row
  float wf = (c < m) ? cnorm[idx] : 0.0f;
  int wb = __float_as_int(wf);
  for (int e = 0; e < m; e += 8) {
    #pragma unroll
    for (int u = 0; u < 8; u++) {
      int   off = __builtin_amdgcn_readlane(sv, e + u);
      float w   = __int_as_float(__builtin_amdgcn_readlane(wb, e + u));
      const ushort* p = hb + off;
      float2 f01 = __half22float2(*(const __half2*)(p + 2 * c));
      float  t2v = __half2float(*(const __half*)(p + 128 + c));
      acc0 += w * f01.x;
      acc1 += w * f01.y;
      acc2 += w * t2v;
    }
  }
  float di = dinv[n];
  float s2 = di * di;
  const ushort* sr = hb + (size_t)n * 192;
  float2 fs = __half22float2(*(const __half2*)(sr + 2 * c));
  float  fst = __half2float(*(const __half*)(sr + 128 + c));
  int oh = ((c >> 5) << 5) + kperm(c & 31);  // kperm'd within-row position
  ushort* orow = ah16 + ((size_t)(b * N_NODES + n)) * 192 + oh;
  *(__half*)&orow[0]   = __float2half_rn(acc0 + s2 * fs.x);   // t3=0 row
  *(__half*)&orow[64]  = __float2half_rn(acc1 + s2 * fs.y);   // t3=1 row
  *(__half*)&orow[128] = __float2half_rn(acc2 + s2 * fst);    // t3=2 row
}

// ---------------- fused epilogue v6: fp16 MFMA, fp16-kperm'd ah, 4 blocks/CU ----------------
// v5 (46us) was staging/latency-bound: MFMA work ~1us/CU; A-read 61MB fp32; 3 blocks/CU.
// v6: (a) ah16 is fp16 + kperm'd -> As staging = 3 uint4 copies/thread (no cvt), A-read
// 30.7MB; (b) red overlaps dead spL -> LDS 40,960B = 160KB/4 -> 4 blocks/CU, 16 waves/CU.
// Fragment maps (HW-verified round 6): A elem j <-> k = s*32 + 16*(j>>2) + 4g + (j&3);
// D: col = lane&15, row = 4*(lane>>4) + reg.
__global__ __launch_bounds__(256, 4) void k_fused(const ushort* __restrict__ ah16,
                                                  const ushort* __restrict__ W2t,
                                                  const float* __restrict__ b2,
                                                  const ushort* __restrict__ p1ct,
                                                  const float* __restrict__ pb1,
                                                  const ushort* __restrict__ p2ct,
                                                  const float* __restrict__ tc2b,
                                                  const float* __restrict__ ow,
                                                  const float* __restrict__ obp,
                                                  float* __restrict__ out) {
  __shared__ __align__(16) ushort smem[20480];     // 40,960 B -> 4 blocks/CU
  ushort* spL = smem;                              // [32][192]
  ushort* As  = smem + 6144;                       // [96][64]   (phase 1)
  ushort* W2s = smem + 12288;                      // [64][64]   (phase 1)
  ushort* Wc  = smem + 6144;                       // [128][64] chunk / [64][128] p2c
  ushort* t1L = smem + 16384;                      // [32][128]
  float*  red = (float*)smem;                      // [4][32] floats; overlays dead spL

  int tid = threadIdx.x;
  int lane = tid & 63, w = tid >> 6;
  int l15 = lane & 15, g = lane >> 4;
  size_t nodeBase = (size_t)blockIdx.x * 32;       // in (b*N+n) units
  const ushort* A16 = ah16 + nodeBase * 192;       // 96 rows x 64 halves, kperm'd

  // ---- stage As: straight 16B-chunk copy, XOR bank-swizzle on the LDS side
  #pragma unroll
  for (int rep = 0; rep < 3; rep++) {
    int idx = rep * 256 + tid;                     // 768 chunks of 8 halves
    int m = idx >> 3, j = idx & 7;
    *(uint4*)&As[m * 64 + ((j ^ (m & 7)) << 3)] = *(const uint4*)&A16[m * 64 + (j << 3)];
  }
  // ---- stage W2s (already fp16+permuted in global; add swizzle)
  #pragma unroll
  for (int r = 0; r < 2; r++) {
    int u = r * 256 + tid;                         // 512 x 8 halves
    int cl = u >> 3, hu = u & 7;
    *(uint4*)&W2s[cl * 64 + ((hu * 8) ^ ((cl & 7) << 3))] =
        *(const uint4*)&W2t[cl * 64 + hu * 8];
  }
  __syncthreads();

  // ---- phase 1: sp = relu(As[96x64] @ W2[64x64] + b2); wave w = cols 16w..16w+15
  {
    int col = w * 16 + l15;
    float bias = b2[col];
    f32x4 acc[6];
    #pragma unroll
    for (int i = 0; i < 6; i++) acc[i] = (f32x4){0.f, 0.f, 0.f, 0.f};
    #pragma unroll
    for (int s = 0; s < 2; s++) {
      int oh = s * 32 + 8 * g;
      f16x8 bf = *(const f16x8*)&W2s[col * 64 + (oh ^ ((col & 7) << 3))];
      #pragma unroll
      for (int mi = 0; mi < 6; mi++) {
        int row = mi * 16 + l15;
        f16x8 af = *(const f16x8*)&As[row * 64 + (oh ^ ((row & 7) << 3))];
        acc[mi] = __builtin_amdgcn_mfma_f32_16x16x32_f16(af, bf, acc[mi], 0, 0, 0);
      }
    }
    // epilogue: D row m=(3n+t3) col c -> spL A-layout row n, k = t3*64+c (perm+swz)
    #pragma unroll
    for (int mi = 0; mi < 6; mi++) {
      #pragma unroll
      for (int r = 0; r < 4; r++) {
        int m = mi * 16 + 4 * g + r;
        int n = m / 3, t3 = m - 3 * n;
        float v = fmaxf(acc[mi][r] + bias, 0.0f);
        int k = t3 * 64 + col;
        int oh = (k >> 5) * 32 + kperm(k & 31);
        *(_Float16*)&spL[n * 192 + (oh ^ ((n & 7) << 3))] = (_Float16)v;
      }
    }
  }
  __syncthreads();                                 // As/W2s dead; spL ready

  // ---- phase 2: t1 = relu(spL[32x192] @ p1c[192x128] + pb1); 3 K-chunks of 64
  f32x4 acc2[2][2];
  #pragma unroll
  for (int i = 0; i < 2; i++)
    #pragma unroll
    for (int j = 0; j < 2; j++) acc2[i][j] = (f32x4){0.f, 0.f, 0.f, 0.f};
  int c0 = 32 * w + l15, c1 = c0 + 16;             // wave w cols {32w..+15, 32w+16..+31}
  for (int cc = 0; cc < 3; cc++) {
    #pragma unroll
    for (int r = 0; r < 4; r++) {                  // stage [128 col][64 k] chunk
      int u = r * 256 + tid;
      int cl = u >> 3, hu = u & 7;
      *(uint4*)&Wc[cl * 64 + ((hu * 8) ^ ((cl & 7) << 3))] =
          *(const uint4*)&p1ct[cl * 192 + cc * 64 + hu * 8];
    }
    __syncthreads();
    #pragma unroll
    for (int ks = 0; ks < 2; ks++) {
      int ohB = ks * 32 + 8 * g;
      f16x8 bf0 = *(const f16x8*)&Wc[c0 * 64 + (ohB ^ ((c0 & 7) << 3))];
      f16x8 bf1 = *(const f16x8*)&Wc[c1 * 64 + (ohB ^ ((c1 & 7) << 3))];
      int ohA = (cc * 2 + ks) * 32 + 8 * g;
      #pragma unroll
      for (int mi = 0; mi < 2; mi++) {
        int row = mi * 16 + l15;
        f16x8 af = *(const f16x8*)&spL[row * 192 + (ohA ^ ((row & 7) << 3))];
        acc2[mi][0] = __builtin_amdgcn_mfma_f32_16x16x32_f16(af, bf0, acc2[mi][0], 0, 0, 0);
        acc2[mi][1] = __builtin_amdgcn_mfma_f32_16x16x32_f16(af, bf1, acc2[mi][1], 0, 0, 0);
      }
    }
    __syncthreads();
  }
  // epilogue: t1L A-layout row n, k = col (perm+swz)
  {
    float bz0 = pb1[c0], bz1 = pb1[c1];
    int oh0 = (c0 >> 5) * 32 + kperm(c0 & 31);
    int oh1 = (c1 >> 5) * 32 + kperm(c1 & 31);
    #pragma unroll
    for (int mi = 0; mi < 2; mi++) {
      #pragma unroll
      for (int r = 0; r < 4; r++) {
        int n = mi * 16 + 4 * g + r;
        float v0 = fmaxf(acc2[mi][0][r] + bz0, 0.0f);
        float v1 = fmaxf(acc2[mi][1][r] + bz1, 0.0f);
        *(_Float16*)&t1L[n * 128 + (oh0 ^ ((n & 7) << 3))] = (_Float16)v0;
        *(_Float16*)&t1L[n * 128 + (oh1 ^ ((n & 7) << 3))] = (_Float16)v1;
      }
    }
  }
  // ---- stage p2cs [64 col][128 k] into Wc (t1L and Wc disjoint; one barrier)
  #pragma unroll
  for (int r = 0; r < 4; r++) {
    int u = r * 256 + tid;                         // 1024 x 8 halves
    int cl = u >> 4, hu = u & 15;
    *(uint4*)&Wc[cl * 128 + ((hu * 8) ^ ((cl & 7) << 3))] =
        *(const uint4*)&p2ct[cl * 128 + hu * 8];
  }
  __syncthreads();

  // ---- phase 3: last = relu(t1L[32x128] @ p2c[128x64] + tc2b); dot with ow
  {
    int col = 16 * w + l15;
    f32x4 acc3[2];
    acc3[0] = (f32x4){0.f, 0.f, 0.f, 0.f};
    acc3[1] = (f32x4){0.f, 0.f, 0.f, 0.f};
    #pragma unroll
    for (int s = 0; s < 4; s++) {
      int oh = s * 32 + 8 * g;
      f16x8 bf = *(const f16x8*)&Wc[col * 128 + (oh ^ ((col & 7) << 3))];
      #pragma unroll
      for (int mi = 0; mi < 2; mi++) {
        int row = mi * 16 + l15;
        f16x8 af = *(const f16x8*)&t1L[row * 128 + (oh ^ ((row & 7) << 3))];
        acc3[mi] = __builtin_amdgcn_mfma_f32_16x16x32_f16(af, bf, acc3[mi], 0, 0, 0);
      }
    }
    float tb = tc2b[col], o4 = ow[col];
    float s4[2][4];
    #pragma unroll
    for (int mi = 0; mi < 2; mi++)
      #pragma unroll
      for (int r = 0; r < 4; r++)
        s4[mi][r] = fmaxf(acc3[mi][r] + tb, 0.0f) * o4;
    #pragma unroll
    for (int off = 1; off <= 8; off <<= 1) {
      #pragma unroll
      for (int mi = 0; mi < 2; mi++)
        #pragma unroll
        for (int r = 0; r < 4; r++)
          s4[mi][r] += __shfl_xor(s4[mi][r], off, 64);
    }
    if (l15 == 0) {
      #pragma unroll
      for (int mi = 0; mi < 2; mi++) {
        float4 o;
        o.x = s4[mi][0]; o.y = s4[mi][1]; o.z = s4[mi][2]; o.w = s4[mi][3];
        *(float4*)&red[w * 32 + mi * 16 + 4 * g] = o;
      }
    }
  }
  __syncthreads();
  if (tid < 32) {
    float v = red[tid] + red[32 + tid] + red[64 + tid] + red[96 + tid] + obp[0];
    out[nodeBase + tid] = v;
  }
}

// ---------------- launch ----------------

extern "C" void kernel_launch(void* const* d_in, const int* in_sizes, int n_in,
                              void* d_out, int out_size, void* d_ws, size_t ws_size,
                              hipStream_t stream) {
  const float* X    = (const float*)d_in[0];
  const int*   EI   = (const int*)  d_in[1];
  const float* EW   = (const float*)d_in[2];
  const float* W1   = (const float*)d_in[3];
  const float* B1   = (const float*)d_in[4];
  const float* W2   = (const float*)d_in[5];
  const float* B2   = (const float*)d_in[6];
  const float* TC1W = (const float*)d_in[7];
  const float* TC1B = (const float*)d_in[8];
  const float* TC2W = (const float*)d_in[9];
  const float* TC2B = (const float*)d_in[10];
  const float* OW   = (const float*)d_in[11];
  const float* OB   = (const float*)d_in[12];
  float* out = (float*)d_out;

  char* base = (char*)d_ws;
  size_t off = 0;
  auto alloc = [&](size_t bytes) -> char* {
    char* p = base + off;
    off += (bytes + 255) & ~(size_t)255;
    return p;
  };
  float*  dinv  = (float*) alloc(N_NODES * 4);
  int*    cur   = (int*)   alloc(N_NODES * 4);
  int*    mcnt  = (int*)   alloc(N_NODES * 4);
  int*    csrc  = (int*)   alloc((size_t)N_NODES * CAP * 4);
  float*  cnorm = (float*) alloc((size_t)N_NODES * CAP * 4);
  ushort* p1ct  = (ushort*)alloc(128 * 192 * 2);
  ushort* p2ct  = (ushort*)alloc(64 * 128 * 2);
  ushort* W2t   = (ushort*)alloc(64 * 64 * 2);
  float*  pb1   = (float*) alloc(128 * 4);
  const size_t BIG = (size_t)80000 * 192;
  ushort* h1   = (ushort*)alloc(BIG * 2);  // fp16 h1: 3.84 MB/batch slab (L2-resident)
  ushort* ah16 = (ushort*)alloc(BIG * 2);  // fp16 kperm'd ah: 30.7 MB

  hipMemsetAsync(cur, 0, N_NODES * 4, stream);
  k_fillfix<<<625, 256, 0, stream>>>(EI, EW, cur, csrc, cnorm);
  k_degpad<<<2500, 256, 0, stream>>>(cur, csrc, cnorm, dinv, mcnt);
  // wnorm (blocks 0..2499) + fp16 transposed/permuted weight pack (blocks 2500..2644)
  k_wnormpack<<<2645, 256, 0, stream>>>(cur, csrc, dinv, cnorm, TC1W, TC2W, TC1B, W2,
                                        p1ct, p2ct, W2t, pb1);

  // layer 1 (agg + W1 + relu), t=9..11 fused; h1 fp16 packed (t0,t1 half2 | t2)
  k_aggg1<<<20000, 256, 0, stream>>>(X, dinv, mcnt, csrc, cnorm, W1, B1, h1);
  // layer 2 aggregation: fp16 L2-resident gather; output fp16 + kperm'd
  k_agg3m16<<<20000, 256, 0, stream>>>(h1, dinv, mcnt, csrc, cnorm, ah16);
  // fused W2-GEMM + conv1 + conv2 + out: v6 (fp16 ah, 4 blocks/CU)
  k_fused<<<2500, 256, 0, stream>>>(ah16, W2t, B2, p1ct, pb1, p2ct, TC2B, OW, OB, out);
}